// Round 7
// baseline (201.587 us; speedup 1.0000x reference)
//
#include <hip/hip_runtime.h>
#include <math.h>

#define BATCH   2
#define T_SEQ   2048
#define DMODEL  1024
#define NHEAD   16
#define HDIM    64

typedef short s16x8 __attribute__((ext_vector_type(8)));
typedef unsigned short u16x8 __attribute__((ext_vector_type(8)));
typedef unsigned short u16x4 __attribute__((ext_vector_type(4)));
typedef unsigned int u32x2 __attribute__((ext_vector_type(2)));
typedef float f32x4 __attribute__((ext_vector_type(4)));

typedef const unsigned int __attribute__((address_space(1))) GUI;
typedef unsigned int __attribute__((address_space(3))) LUI;

// fp32 -> bf16 round-to-nearest-even (bit pattern)
static __device__ __forceinline__ unsigned short f2bf(float f) {
    unsigned int u = __float_as_uint(f);
    u += 0x7fffu + ((u >> 16) & 1u);
    return (unsigned short)(u >> 16);
}

// two fp32 -> packed bf16x2 (round-half-up) via one v_perm_b32
static __device__ __forceinline__ unsigned int f2bf_pack2(float a, float b) {
    const unsigned int ua = __float_as_uint(a) + 0x8000u;
    const unsigned int ub = __float_as_uint(b) + 0x8000u;
    return __builtin_amdgcn_perm(ub, ua, 0x07060302u);
}

// ---------------------------------------------------------------------------
// Fused prep: blocks 0..2047 convert x -> bf16; 2048..2815 transpose Wqkv;
// 2816..3071 transpose Wout; 3072..3327 build RoPE cos/sin table
// ---------------------------------------------------------------------------
__global__ __launch_bounds__(256) void prep_fused(
    const float* __restrict__ x, const float* __restrict__ Wqkv,
    const float* __restrict__ Wout,
    unsigned short* __restrict__ xb, unsigned short* __restrict__ Wqkv_t,
    unsigned short* __restrict__ Wout_t, float2* __restrict__ rope_tab)
{
    __shared__ unsigned short tile[64][68];
    const int bid = blockIdx.x;
    const int tid = threadIdx.x;

    if (bid < 2048) {
        const int i = bid * 256 + tid;
        const float4 a = ((const float4*)x)[2 * i];
        const float4 b = ((const float4*)x)[2 * i + 1];
        u16x8 r;
        r[0] = f2bf(a.x); r[1] = f2bf(a.y); r[2] = f2bf(a.z); r[3] = f2bf(a.w);
        r[4] = f2bf(b.x); r[5] = f2bf(b.y); r[6] = f2bf(b.z); r[7] = f2bf(b.w);
        ((u16x8*)xb)[i] = r;
        return;
    }
    if (bid >= 3072) {
        const int idx = (bid - 3072) * 256 + tid;
        const int t = idx >> 5;
        const int d2 = idx & 31;
        const float inv_freq = exp2f(-(float)d2 * 0.41524101186092029f); // log2(1e4)/32
        float s, c;
        sincosf((float)t * inv_freq, &s, &c);
        rope_tab[idx] = make_float2(c, s);
        return;
    }

    const float* src;
    unsigned short* dst;
    int R, C, bx, by;
    if (bid < 2816) {
        const int id = bid - 2048;
        src = Wqkv; dst = Wqkv_t; R = DMODEL; C = 3 * DMODEL;
        bx = id % 48; by = id / 48;
    } else {
        const int id = bid - 2816;
        src = Wout; dst = Wout_t; R = DMODEL; C = DMODEL;
        bx = id % 16; by = id / 16;
    }
    const int tc0 = bx * 64;
    const int tr0 = by * 64;
    const int tx = tid & 63;
    const int ty = tid >> 6;
#pragma unroll
    for (int i = 0; i < 16; i++) {
        const int rr = i * 4 + ty;
        tile[tx][rr] = f2bf(src[(size_t)(tr0 + rr) * C + tc0 + tx]);
    }
    __syncthreads();
#pragma unroll
    for (int i = 0; i < 16; i++) {
        const int cc = i * 4 + ty;
        dst[(size_t)(tc0 + cc) * R + tr0 + tx] = tile[cc][tx];
    }
}

// ---------------------------------------------------------------------------
// Shared MFMA GEMM main loop, DOUBLE-BUFFERED, one barrier per K-slice.
// (Round-0 proven form — do not touch; see session notes.)
// ---------------------------------------------------------------------------
__device__ __forceinline__ void mfma_gemm_loop_db(
    const unsigned short* __restrict__ A, const unsigned short* __restrict__ Bt,
    unsigned short* As, unsigned short* Bs,
    int m0, int n0, int K, f32x4 acc[4][4])
{
    const int tid  = threadIdx.x;
    const int wave = tid >> 6;
    const int lane = tid & 63;
    const int quad = lane >> 4;
    const int lc   = lane & 15;
    const int wr   = (wave >> 1) * 64;
    const int wc   = (wave & 1) * 64;

    const int c0    = wave * 2;
    const int srow0 = c0 * 16 + (lane >> 2);
    const int scol  = (lane & 3) * 8;

#pragma unroll
    for (int i = 0; i < 4; i++)
#pragma unroll
        for (int j = 0; j < 4; j++)
            acc[i][j] = (f32x4){0.f, 0.f, 0.f, 0.f};

    auto stage = [&](int kt, int buf) {
        const unsigned short* ga0 = A + (size_t)(m0 + srow0) * K + kt + scol;
        const unsigned short* ga1 = A + (size_t)(m0 + srow0 + 16) * K + kt + scol;
        const unsigned short* gb0 = Bt + (size_t)(n0 + srow0) * K + kt + scol;
        const unsigned short* gb1 = Bt + (size_t)(n0 + srow0 + 16) * K + kt + scol;
        unsigned short* as = As + buf * 4096;
        unsigned short* bs = Bs + buf * 4096;
        __builtin_amdgcn_global_load_lds((GUI*)ga0, (LUI*)(as + c0 * 512 + lane * 8), 16, 0, 0);
        __builtin_amdgcn_global_load_lds((GUI*)ga1, (LUI*)(as + (c0 + 1) * 512 + lane * 8), 16, 0, 0);
        __builtin_amdgcn_global_load_lds((GUI*)gb0, (LUI*)(bs + c0 * 512 + lane * 8), 16, 0, 0);
        __builtin_amdgcn_global_load_lds((GUI*)gb1, (LUI*)(bs + (c0 + 1) * 512 + lane * 8), 16, 0, 0);
    };

    stage(0, 0);
    const int nit = K >> 5;
    for (int it = 0; it < nit; ++it) {
        __syncthreads();
        if (it + 1 < nit) stage((it + 1) << 5, (it + 1) & 1);

        const unsigned short* as = As + (it & 1) * 4096;
        const unsigned short* bs = Bs + (it & 1) * 4096;
        s16x8 a[4], b[4];
#pragma unroll
        for (int mt = 0; mt < 4; mt++)
            a[mt] = *(const s16x8*)(as + (wr + mt * 16 + lc) * 32 + quad * 8);
#pragma unroll
        for (int nb = 0; nb < 4; nb++)
            b[nb] = *(const s16x8*)(bs + (wc + nb * 16 + lc) * 32 + quad * 8);
#pragma unroll
        for (int mt = 0; mt < 4; mt++)
#pragma unroll
            for (int nb = 0; nb < 4; nb++)
                acc[mt][nb] = __builtin_amdgcn_mfma_f32_16x16x32_bf16(a[mt], b[nb], acc[mt][nb], 0, 0, 0);
    }
}

// ---------------------------------------------------------------------------
// QKV GEMM (bf16 MFMA, dbuf) + RoPE (table lookup) + Q-scale + pack.
// 1-D grid 768, XCD-affine. (Round-0 proven version: ~48 us.)
// ---------------------------------------------------------------------------
__global__ __launch_bounds__(256) void gemm_qkv_rope_mfma(
    const unsigned short* __restrict__ xb, const unsigned short* __restrict__ Wt,
    const float2* __restrict__ rope_tab,
    unsigned short* __restrict__ Qb, unsigned short* __restrict__ Kb,
    unsigned short* __restrict__ Vb)
{
    __shared__ __align__(16) unsigned short As[2 * 128 * 32];
    __shared__ __align__(16) unsigned short Bs[2 * 128 * 32];

    const int id  = blockIdx.x;               // 0..767
    const int s   = id >> 3;                  // 0..95
    const int n0  = ((id & 7) * 3 + (s % 3)) * 128;
    const int m0  = (s / 3) * 128;
    f32x4 acc[4][4];
    mfma_gemm_loop_db(xb, Wt, As, Bs, m0, n0, DMODEL, acc);

    const int lane = threadIdx.x & 63;
    const int wave = threadIdx.x >> 6;
    const int quad = lane >> 4;
    const int lc   = lane & 15;
    const int wr   = (wave >> 1) * 64;
    const int wc   = (wave & 1) * 64;

    const int n_base = n0 + wc;
    const int part = n_base >> 10;       // 0=q 1=k 2=v, uniform per block
    unsigned short* dst = (part == 0) ? Qb : (part == 1 ? Kb : Vb);
    const float scale = (part == 0) ? 0.125f * 1.4426950408889634f : 1.0f;

#pragma unroll
    for (int nb = 0; nb < 4; nb++) {
        const int n = n_base + nb * 16 + lc;
        const int h = (n >> 6) & 15;
        const int d = n & 63;
        if (part == 2) {
#pragma unroll
            for (int mt = 0; mt < 4; mt++) {
                const int mb = m0 + wr + mt * 16 + quad * 4;
                const int bb = mb >> 11, t = mb & 2047;
                u16x4 pk;
                pk[0] = f2bf(acc[mt][nb][0]); pk[1] = f2bf(acc[mt][nb][1]);
                pk[2] = f2bf(acc[mt][nb][2]); pk[3] = f2bf(acc[mt][nb][3]);
                *(u16x4*)&dst[((size_t)(bb * NHEAD + h) * HDIM + d) * T_SEQ + t] = pk;
            }
        } else {
            const size_t hb = (size_t)h * T_SEQ * HDIM + d;
            const int d2 = d >> 1;
            const float ssign = (lc & 1) ? 1.f : -1.f;
#pragma unroll
            for (int mt = 0; mt < 4; mt++) {
                const int mb = m0 + wr + mt * 16 + quad * 4;
#pragma unroll
                for (int r = 0; r < 4; r++) {
                    const float val = acc[mt][nb][r];
                    const float prt = __shfl_xor(val, 1);
                    const int m = mb + r;
                    const int bb = m >> 11, t = m & 2047;
                    const float2 sc = rope_tab[t * 32 + d2];   // (cos, sin)
                    const float res = fmaf(prt, ssign * sc.y, val * sc.x) * scale;
                    dst[(size_t)bb * NHEAD * T_SEQ * HDIM + hb + (size_t)t * HDIM] = f2bf(res);
                }
            }
        }
    }
}

// ---------------------------------------------------------------------------
// Out-proj GEMM v2: 128x64 tile, grid 512 = 2 blocks/CU.
// ---------------------------------------------------------------------------
__global__ __launch_bounds__(256) void gemm_out_mfma(
    const unsigned short* __restrict__ A, const unsigned short* __restrict__ Bt,
    float* __restrict__ C, int N, int K)
{
    __shared__ __align__(16) unsigned short As[2 * 128 * 32];  // 16 KB
    __shared__ __align__(16) unsigned short Bs[2 * 64 * 32];   //  8 KB

    const int id = blockIdx.x;            // 0..511
    const int s  = id >> 3;               // 0..63
    const int n0 = ((id & 7) * 2 + (s & 1)) * 64;   // 16 n-blocks, XCD-affine
    const int m0 = (s >> 1) * 128;                  // 32 m-blocks

    const int tid  = threadIdx.x;
    const int wave = tid >> 6;
    const int lane = tid & 63;
    const int quad = lane >> 4;
    const int lc   = lane & 15;
    const int wr   = wave * 32;           // 4 waves stacked along M

    const int c0    = wave * 2;
    const int arow0 = c0 * 16 + (lane >> 2);        // A stage rows (128)
    const int brow0 = wave * 16 + (lane >> 2);      // B stage rows (64)
    const int scol  = (lane & 3) * 8;

    f32x4 acc[2][4];
#pragma unroll
    for (int i = 0; i < 2; i++)
#pragma unroll
        for (int j = 0; j < 4; j++)
            acc[i][j] = (f32x4){0.f, 0.f, 0.f, 0.f};

    auto stage = [&](int kt, int buf) {
        const unsigned short* ga0 = A + (size_t)(m0 + arow0) * K + kt + scol;
        const unsigned short* ga1 = A + (size_t)(m0 + arow0 + 16) * K + kt + scol;
        const unsigned short* gb0 = Bt + (size_t)(n0 + brow0) * K + kt + scol;
        unsigned short* as = As + buf * 4096;
        unsigned short* bs = Bs + buf * 2048;
        __builtin_amdgcn_global_load_lds((GUI*)ga0, (LUI*)(as + c0 * 512 + lane * 8), 16, 0, 0);
        __builtin_amdgcn_global_load_lds((GUI*)ga1, (LUI*)(as + (c0 + 1) * 512 + lane * 8), 16, 0, 0);
        __builtin_amdgcn_global_load_lds((GUI*)gb0, (LUI*)(bs + wave * 512 + lane * 8), 16, 0, 0);
    };

    stage(0, 0);
    const int nit = K >> 5;
    for (int it = 0; it < nit; ++it) {
        __syncthreads();
        if (it + 1 < nit) stage((it + 1) << 5, (it + 1) & 1);

        const unsigned short* as = As + (it & 1) * 4096;
        const unsigned short* bs = Bs + (it & 1) * 2048;
        s16x8 a[2], b[4];
#pragma unroll
        for (int mt = 0; mt < 2; mt++)
            a[mt] = *(const s16x8*)(as + (wr + mt * 16 + lc) * 32 + quad * 8);
#pragma unroll
        for (int nb = 0; nb < 4; nb++)
            b[nb] = *(const s16x8*)(bs + (nb * 16 + lc) * 32 + quad * 8);
#pragma unroll
        for (int mt = 0; mt < 2; mt++)
#pragma unroll
            for (int nb = 0; nb < 4; nb++)
                acc[mt][nb] = __builtin_amdgcn_mfma_f32_16x16x32_bf16(a[mt], b[nb], acc[mt][nb], 0, 0, 0);
    }

#pragma unroll
    for (int mt = 0; mt < 2; mt++) {
        const int mb = m0 + wr + mt * 16 + quad * 4;
#pragma unroll
        for (int r = 0; r < 4; r++) {
            float* row = C + (size_t)(mb + r) * N + n0;
#pragma unroll
            for (int nb = 0; nb < 4; nb++)
                row[nb * 16 + lc] = acc[mt][nb][r];
        }
    }
}

// ---------------------------------------------------------------------------
// MFMA causal flash attention v10: 128-row q-superblock per block, TWO
// independent softmax pipelines (low/high 64-row q-tiles) sharing the K/V
// stream. Rationale: v8/v9 were chain-latency-bound (all 4 waves of a block
// stall on the same serial softmax chain; extra blocks/CU didn't overlap it).
// Two independent chains per wave interleave in the scheduler, and the
// ka/va fragment reads + K/V staging are shared (half the LDS traffic per
// unit of work). Grid 512 (16 sb x 32 bh, longest-first, id%8=bh%8 keeps
// XCD affinity), 2 blocks/CU -> VGPR budget 256 at 2 waves/SIMD.
// Hot loop tiles 0..2sb run both pipelines (low masked at tk==2sb); one
// peeled tile (tk=2sb+1) runs the high diagonal alone.
// ---------------------------------------------------------------------------
__global__ __launch_bounds__(256, 2) void attn_mfma10(
    const unsigned short* __restrict__ Qb, const unsigned short* __restrict__ Kb,
    const unsigned short* __restrict__ Vtg, unsigned short* __restrict__ out)
{
    __shared__ __align__(16) unsigned short Ks[2][64 * 64];
    __shared__ __align__(16) unsigned short Vs[2][64 * 64];
    __shared__ __align__(16) unsigned short Ps[2][4][16 * 72];

    const int tid  = threadIdx.x;
    const int lane = tid & 63;
    const int wave = tid >> 6;           // 0..3
    const int quad = lane >> 4;
    const int lc   = lane & 15;
    const int rsw  = lc & 7;

    const int id   = blockIdx.x;             // 0..511
    const int bh   = id & 31;                // id%8==bh%8 -> XCD-affine
    const int sb   = 15 - (id >> 5);         // longest superblocks first
    const int t0   = sb * 128;

    const size_t headK = (size_t)bh * T_SEQ * HDIM;   // Q,K: (BH,T,64)
    const size_t headV = (size_t)bh * HDIM * T_SEQ;   // Vt:  (BH,64,T)
    const int b = bh >> 4;
    const int h = bh & 15;

    const int c0   = wave * 2;
    const int krow = lane >> 3;
    const int d8sw = (lane & 7) ^ krow;
    unsigned short* pwl = Ps[0][wave];
    unsigned short* pwh = Ps[1][wave];

    // Q fragments for both q-tiles
    s16x8 qf0l, qf1l, qf0h, qf1h;
    {
        const size_t qrl = headK + (size_t)(t0 + wave * 16 + lc) * HDIM;
        qf0l = *(const s16x8*)(Qb + qrl + quad * 8);
        qf1l = *(const s16x8*)(Qb + qrl + 32 + quad * 8);
        const size_t qrh = qrl + (size_t)64 * HDIM;
        qf0h = *(const s16x8*)(Qb + qrh + quad * 8);
        qf1h = *(const s16x8*)(Qb + qrh + 32 + quad * 8);
    }

    f32x4 ol[4], oh[4];
    float m_l = -INFINITY, l_l = 0.f;
    float m_h = -INFINITY, l_h = 0.f;
#pragma unroll
    for (int db = 0; db < 4; db++) {
        ol[db] = (f32x4){0.f, 0.f, 0.f, 0.f};
        oh[db] = (f32x4){0.f, 0.f, 0.f, 0.f};
    }

    auto stage = [&](int s0, int buf) {
        const unsigned short* gk0 = Kb  + headK + (size_t)(s0 + c0 * 8 + krow) * HDIM + d8sw * 8;
        const unsigned short* gk1 = Kb  + headK + (size_t)(s0 + c0 * 8 + 8 + krow) * HDIM + d8sw * 8;
        const unsigned short* gv0 = Vtg + headV + (size_t)(c0 * 8 + krow) * T_SEQ + s0 + d8sw * 8;
        const unsigned short* gv1 = Vtg + headV + (size_t)(c0 * 8 + 8 + krow) * T_SEQ + s0 + d8sw * 8;
        __builtin_amdgcn_global_load_lds((GUI*)gk0, (LUI*)(Ks[buf] + c0 * 512 + lane * 8), 16, 0, 0);
        __builtin_amdgcn_global_load_lds((GUI*)gk1, (LUI*)(Ks[buf] + (c0 + 1) * 512 + lane * 8), 16, 0, 0);
        __builtin_amdgcn_global_load_lds((GUI*)gv0, (LUI*)(Vs[buf] + c0 * 512 + lane * 8), 16, 0, 0);
        __builtin_amdgcn_global_load_lds((GUI*)gv1, (LUI*)(Vs[buf] + (c0 + 1) * 512 + lane * 8), 16, 0, 0);
    };

    const int last_tk = 2 * sb + 1;          // peeled high-diagonal tile
    stage(0, 0);

    // ---- hot loop: both pipelines active, tiles 0..2sb
    for (int tk = 0; tk <= 2 * sb; ++tk) {
        const int s0 = tk * 64;
        const int buf = tk & 1;
        __syncthreads();
        stage(s0 + 64, buf ^ 1);             // tk+1 <= 2sb+1 = last tile: valid

        const unsigned short* ks = Ks[buf];
        const unsigned short* vs = Vs[buf];

        // QK^T for both pipelines, shared K fragments
        f32x4 stl[4], sth[4];
        __builtin_amdgcn_s_setprio(1);
#pragma unroll
        for (int kb = 0; kb < 4; kb++) {
            const s16x8 ka0 = *(const s16x8*)&ks[(kb * 16 + lc) * 64 + ((quad ^ rsw) * 8)];
            const s16x8 ka1 = *(const s16x8*)&ks[(kb * 16 + lc) * 64 + (((4 + quad) ^ rsw) * 8)];
            f32x4 zl = (f32x4){0.f, 0.f, 0.f, 0.f};
            zl = __builtin_amdgcn_mfma_f32_16x16x32_bf16(ka0, qf0l, zl, 0, 0, 0);
            zl = __builtin_amdgcn_mfma_f32_16x16x32_bf16(ka1, qf1l, zl, 0, 0, 0);
            stl[kb] = zl;
            f32x4 zh = (f32x4){0.f, 0.f, 0.f, 0.f};
            zh = __builtin_amdgcn_mfma_f32_16x16x32_bf16(ka0, qf0h, zh, 0, 0, 0);
            zh = __builtin_amdgcn_mfma_f32_16x16x32_bf16(ka1, qf1h, zh, 0, 0, 0);
            sth[kb] = zh;
        }
        __builtin_amdgcn_s_setprio(0);

        s16x8 va[4][2];
#pragma unroll
        for (int db = 0; db < 4; db++) {
            va[db][0] = *(const s16x8*)&vs[(db * 16 + lc) * 64 + ((quad ^ rsw) * 8)];
            va[db][1] = *(const s16x8*)&vs[(db * 16 + lc) * 64 + (((4 + quad) ^ rsw) * 8)];
        }

        // causal mask: low pipeline's diagonal is the last hot-loop tile
        if (tk == 2 * sb) {
            const int qrow = t0 + wave * 16 + lc;
#pragma unroll
            for (int kb = 0; kb < 4; kb++) {
                const int key = s0 + kb * 16 + quad * 4;
#pragma unroll
                for (int r = 0; r < 4; r++)
                    if (key + r > qrow) stl[kb][r] = -INFINITY;
            }
        }

        // ---- softmax, both pipelines (independent chains interleave)
        float xl0 = fmaxf(fmaxf(stl[0][0], stl[0][1]), stl[0][2]);
        float xh0 = fmaxf(fmaxf(sth[0][0], sth[0][1]), sth[0][2]);
        float xl1 = fmaxf(fmaxf(stl[0][3], stl[1][0]), stl[1][1]);
        float xh1 = fmaxf(fmaxf(sth[0][3], sth[1][0]), sth[1][1]);
        float xl2 = fmaxf(fmaxf(stl[1][2], stl[1][3]), stl[2][0]);
        float xh2 = fmaxf(fmaxf(sth[1][2], sth[1][3]), sth[2][0]);
        float xl3 = fmaxf(fmaxf(stl[2][1], stl[2][2]), stl[2][3]);
        float xh3 = fmaxf(fmaxf(sth[2][1], sth[2][2]), sth[2][3]);
        float xl4 = fmaxf(fmaxf(stl[3][0], stl[3][1]), stl[3][2]);
        float xh4 = fmaxf(fmaxf(sth[3][0], sth[3][1]), sth[3][2]);
        float mtl = fmaxf(fmaxf(fmaxf(xl0, xl1), fmaxf(xl2, xl3)),
                          fmaxf(xl4, stl[3][3]));
        float mth = fmaxf(fmaxf(fmaxf(xh0, xh1), fmaxf(xh2, xh3)),
                          fmaxf(xh4, sth[3][3]));
        mtl = fmaxf(mtl, __shfl_xor(mtl, 16));
        mth = fmaxf(mth, __shfl_xor(mth, 16));
        mtl = fmaxf(mtl, __shfl_xor(mtl, 32));
        mth = fmaxf(mth, __shfl_xor(mth, 32));

        // T13 defer-max, per pipeline
        if (!__all(mtl <= m_l + 8.0f)) {
            const float mn = fmaxf(m_l, mtl);
            const float alpha = __builtin_amdgcn_exp2f(m_l - mn);
            m_l = mn;
            l_l *= alpha;
#pragma unroll
            for (int db = 0; db < 4; db++) {
                ol[db][0] *= alpha; ol[db][1] *= alpha;
                ol[db][2] *= alpha; ol[db][3] *= alpha;
            }
        }
        if (!__all(mth <= m_h + 8.0f)) {
            const float mn = fmaxf(m_h, mth);
            const float alpha = __builtin_amdgcn_exp2f(m_h - mn);
            m_h = mn;
            l_h *= alpha;
#pragma unroll
            for (int db = 0; db < 4; db++) {
                oh[db][0] *= alpha; oh[db][1] *= alpha;
                oh[db][2] *= alpha; oh[db][3] *= alpha;
            }
        }

        float rl = 0.f, rh = 0.f;
#pragma unroll
        for (int kb = 0; kb < 4; kb++) {
            const float el0 = __builtin_amdgcn_exp2f(stl[kb][0] - m_l);
            const float eh0 = __builtin_amdgcn_exp2f(sth[kb][0] - m_h);
            const float el1 = __builtin_amdgcn_exp2f(stl[kb][1] - m_l);
            const float eh1 = __builtin_amdgcn_exp2f(sth[kb][1] - m_h);
            const float el2 = __builtin_amdgcn_exp2f(stl[kb][2] - m_l);
            const float eh2 = __builtin_amdgcn_exp2f(sth[kb][2] - m_h);
            const float el3 = __builtin_amdgcn_exp2f(stl[kb][3] - m_l);
            const float eh3 = __builtin_amdgcn_exp2f(sth[kb][3] - m_h);
            stl[kb][0] = el0; stl[kb][1] = el1; stl[kb][2] = el2; stl[kb][3] = el3;
            sth[kb][0] = eh0; sth[kb][1] = eh1; sth[kb][2] = eh2; sth[kb][3] = eh3;
            rl += (el0 + el1) + (el2 + el3);
            rh += (eh0 + eh1) + (eh2 + eh3);
        }
        rl += __shfl_xor(rl, 16);
        rh += __shfl_xor(rh, 16);
        rl += __shfl_xor(rl, 32);
        rh += __shfl_xor(rh, 32);
        l_l += rl;
        l_h += rh;

        // P -> LDS (disjoint buffers), then PV for both, shared V fragments
#pragma unroll
        for (int kb = 0; kb < 4; kb++) {
            u32x2 pkl, pkh;
            pkl[0] = f2bf_pack2(stl[kb][0], stl[kb][1]);
            pkl[1] = f2bf_pack2(stl[kb][2], stl[kb][3]);
            pkh[0] = f2bf_pack2(sth[kb][0], sth[kb][1]);
            pkh[1] = f2bf_pack2(sth[kb][2], sth[kb][3]);
            *(u32x2*)&pwl[lc * 72 + kb * 16 + quad * 4] = pkl;
            *(u32x2*)&pwh[lc * 72 + kb * 16 + quad * 4] = pkh;
        }
        const s16x8 pb0l = *(const s16x8*)&pwl[lc * 72 + quad * 8];
        const s16x8 pb1l = *(const s16x8*)&pwl[lc * 72 + 32 + quad * 8];
        const s16x8 pb0h = *(const s16x8*)&pwh[lc * 72 + quad * 8];
        const s16x8 pb1h = *(const s16x8*)&pwh[lc * 72 + 32 + quad * 8];
        __builtin_amdgcn_s_setprio(1);
#pragma unroll
        for (int db = 0; db < 4; db++) {
            ol[db] = __builtin_amdgcn_mfma_f32_16x16x32_bf16(va[db][0], pb0l, ol[db], 0, 0, 0);
            oh[db] = __builtin_amdgcn_mfma_f32_16x16x32_bf16(va[db][0], pb0h, oh[db], 0, 0, 0);
            ol[db] = __builtin_amdgcn_mfma_f32_16x16x32_bf16(va[db][1], pb1l, ol[db], 0, 0, 0);
            oh[db] = __builtin_amdgcn_mfma_f32_16x16x32_bf16(va[db][1], pb1h, oh[db], 0, 0, 0);
        }
        __builtin_amdgcn_s_setprio(0);
    }

    // ---- peeled tile: high diagonal (tk = 2sb+1), high pipeline only
    {
        const int s0 = last_tk * 64;
        const int buf = last_tk & 1;
        __syncthreads();                      // drain stage issued last iter

        const unsigned short* ks = Ks[buf];
        const unsigned short* vs = Vs[buf];

        f32x4 sth[4];
        __builtin_amdgcn_s_setprio(1);
#pragma unroll
        for (int kb = 0; kb < 4; kb++) {
            const s16x8 ka0 = *(const s16x8*)&ks[(kb * 16 + lc) * 64 + ((quad ^ rsw) * 8)];
            const s16x8 ka1 = *(const s16x8*)&ks[(kb * 16 + lc) * 64 + (((4 + quad) ^ rsw) * 8)];
            f32x4 zh = (f32x4){0.f, 0.f, 0.f, 0.f};
            zh = __builtin_amdgcn_mfma_f32_16x16x32_bf16(ka0, qf0h, zh, 0, 0, 0);
            zh = __builtin_amdgcn_mfma_f32_16x16x32_bf16(ka1, qf1h, zh, 0, 0, 0);
            sth[kb] = zh;
        }
        __builtin_amdgcn_s_setprio(0);

        s16x8 va[4][2];
#pragma unroll
        for (int db = 0; db < 4; db++) {
            va[db][0] = *(const s16x8*)&vs[(db * 16 + lc) * 64 + ((quad ^ rsw) * 8)];
            va[db][1] = *(const s16x8*)&vs[(db * 16 + lc) * 64 + (((4 + quad) ^ rsw) * 8)];
        }

        {
            const int qrow = t0 + 64 + wave * 16 + lc;
#pragma unroll
            for (int kb = 0; kb < 4; kb++) {
                const int key = s0 + kb * 16 + quad * 4;
#pragma unroll
                for (int r = 0; r < 4; r++)
                    if (key + r > qrow) sth[kb][r] = -INFINITY;
            }
        }

        float x0 = fmaxf(fmaxf(sth[0][0], sth[0][1]), sth[0][2]);
        float x1 = fmaxf(fmaxf(sth[0][3], sth[1][0]), sth[1][1]);
        float x2 = fmaxf(fmaxf(sth[1][2], sth[1][3]), sth[2][0]);
        float x3 = fmaxf(fmaxf(sth[2][1], sth[2][2]), sth[2][3]);
        float x4 = fmaxf(fmaxf(sth[3][0], sth[3][1]), sth[3][2]);
        float mth = fmaxf(fmaxf(fmaxf(x0, x1), fmaxf(x2, x3)),
                          fmaxf(x4, sth[3][3]));
        mth = fmaxf(mth, __shfl_xor(mth, 16));
        mth = fmaxf(mth, __shfl_xor(mth, 32));

        if (!__all(mth <= m_h + 8.0f)) {
            const float mn = fmaxf(m_h, mth);
            const float alpha = __builtin_amdgcn_exp2f(m_h - mn);
            m_h = mn;
            l_h *= alpha;
#pragma unroll
            for (int db = 0; db < 4; db++) {
                oh[db][0] *= alpha; oh[db][1] *= alpha;
                oh[db][2] *= alpha; oh[db][3] *= alpha;
            }
        }

        float rh = 0.f;
#pragma unroll
        for (int kb = 0; kb < 4; kb++) {
            const float e0 = __builtin_amdgcn_exp2f(sth[kb][0] - m_h);
            const float e1 = __builtin_amdgcn_exp2f(sth[kb][1] - m_h);
            const float e2 = __builtin_amdgcn_exp2f(sth[kb][2] - m_h);
            const float e3 = __builtin_amdgcn_exp2f(sth[kb][3] - m_h);
            sth[kb][0] = e0; sth[kb][1] = e1; sth[kb][2] = e2; sth[kb][3] = e3;
            rh += (e0 + e1) + (e2 + e3);
        }
        rh += __shfl_xor(rh, 16);
        rh += __shfl_xor(rh, 32);
        l_h += rh;

#pragma unroll
        for (int kb = 0; kb < 4; kb++) {
            u32x2 pk;
            pk[0] = f2bf_pack2(sth[kb][0], sth[kb][1]);
            pk[1] = f2bf_pack2(sth[kb][2], sth[kb][3]);
            *(u32x2*)&pwh[lc * 72 + kb * 16 + quad * 4] = pk;
        }
        const s16x8 pb0 = *(const s16x8*)&pwh[lc * 72 + quad * 8];
        const s16x8 pb1 = *(const s16x8*)&pwh[lc * 72 + 32 + quad * 8];
        __builtin_amdgcn_s_setprio(1);
#pragma unroll
        for (int db = 0; db < 4; db++) {
            oh[db] = __builtin_amdgcn_mfma_f32_16x16x32_bf16(va[db][0], pb0, oh[db], 0, 0, 0);
            oh[db] = __builtin_amdgcn_mfma_f32_16x16x32_bf16(va[db][1], pb1, oh[db], 0, 0, 0);
        }
        __builtin_amdgcn_s_setprio(0);
    }

    // ---- epilogue: both q-tiles
    {
        const float invl = 1.f / l_l;
        const float invh = 1.f / l_h;
        const int tl = t0 + wave * 16 + lc;
        unsigned short* orl = out + (size_t)(b * T_SEQ + tl) * DMODEL + h * HDIM + quad * 4;
        unsigned short* orh = orl + (size_t)64 * DMODEL;
#pragma unroll
        for (int db = 0; db < 4; db++) {
            u32x2 pkl, pkh;
            pkl[0] = f2bf_pack2(ol[db][0] * invl, ol[db][1] * invl);
            pkl[1] = f2bf_pack2(ol[db][2] * invl, ol[db][3] * invl);
            pkh[0] = f2bf_pack2(oh[db][0] * invh, oh[db][1] * invh);
            pkh[1] = f2bf_pack2(oh[db][2] * invh, oh[db][3] * invh);
            *(u32x2*)(orl + db * 16) = pkl;
            *(u32x2*)(orh + db * 16) = pkh;
        }
    }
}

// ---------------------------------------------------------------------------
extern "C" void kernel_launch(void* const* d_in, const int* in_sizes, int n_in,
                              void* d_out, int out_size, void* d_ws, size_t ws_size,
                              hipStream_t stream)
{
    const float* x    = (const float*)d_in[0];   // (B,T,D) fp32
    const float* Wqkv = (const float*)d_in[1];   // (D,3D) fp32
    const float* Wout = (const float*)d_in[2];   // (D,D) fp32
    // d_in[3] attn_mask: causal triu(k=1), applied analytically.

    float* out = (float*)d_out;

    char* ws = (char*)d_ws;
    unsigned short* attnb  = (unsigned short*)(ws);               // (B,T,D) bf16, 8 MB
    unsigned short* Qb     = (unsigned short*)(ws + (8u  << 20)); // (B,H,T,64)
    unsigned short* Kb     = (unsigned short*)(ws + (16u << 20)); // (B,H,T,64)
    unsigned short* Vt     = (unsigned short*)(ws + (24u << 20)); // (B,H,64,T)
    unsigned short* xbuf   = (unsigned short*)(ws + (32u << 20)); // (M,K) bf16
    unsigned short* Wqkv_t = (unsigned short*)(ws + (40u << 20)); // (3D,D) bf16
    unsigned short* Wout_t = (unsigned short*)(ws + (46u << 20)); // (D,D) bf16
    float2*         ropeT  = (float2*)       (ws + (48u << 20)); // 2048x32 float2, 512 KB

    // 0) fused prep: convert x, transpose weights, build RoPE table
    prep_fused<<<dim3(3328), 256, 0, stream>>>(x, Wqkv, Wout, xbuf, Wqkv_t, Wout_t, ropeT);

    // 1) QKV MFMA GEMM (dbuf, XCD-affine) + RoPE table + scale + pack
    gemm_qkv_rope_mfma<<<dim3(768), 256, 0, stream>>>(xbuf, Wqkv_t, ropeT, Qb, Kb, Vt);

    // 2) MFMA causal flash attention v10 (128-row superblock, dual pipeline)
    attn_mfma10<<<dim3(512), 256, 0, stream>>>(Qb, Kb, Vt, attnb);

    // 3) out = attnb @ Wout  (fp32 out, 128x64 tile, 2 blocks/CU)
    gemm_out_mfma<<<dim3(512), 256, 0, stream>>>(attnb, Wout_t, out, DMODEL, DMODEL);
}

// Round 8
// 195.777 us; speedup vs baseline: 1.0297x; 1.0297x over previous
//
#include <hip/hip_runtime.h>
#include <math.h>

#define BATCH   2
#define T_SEQ   2048
#define DMODEL  1024
#define NHEAD   16
#define HDIM    64

typedef short s16x8 __attribute__((ext_vector_type(8)));
typedef unsigned short u16x8 __attribute__((ext_vector_type(8)));
typedef unsigned short u16x4 __attribute__((ext_vector_type(4)));
typedef unsigned int u32x2 __attribute__((ext_vector_type(2)));
typedef float f32x4 __attribute__((ext_vector_type(4)));

typedef const unsigned int __attribute__((address_space(1))) GUI;
typedef unsigned int __attribute__((address_space(3))) LUI;

// fp32 -> bf16 round-to-nearest-even (bit pattern)
static __device__ __forceinline__ unsigned short f2bf(float f) {
    unsigned int u = __float_as_uint(f);
    u += 0x7fffu + ((u >> 16) & 1u);
    return (unsigned short)(u >> 16);
}

// two fp32 -> packed bf16x2 (round-half-up) via one v_perm_b32
static __device__ __forceinline__ unsigned int f2bf_pack2(float a, float b) {
    const unsigned int ua = __float_as_uint(a) + 0x8000u;
    const unsigned int ub = __float_as_uint(b) + 0x8000u;
    return __builtin_amdgcn_perm(ub, ua, 0x07060302u);
}

// ---------------------------------------------------------------------------
// Fused prep: blocks 0..2047 convert x -> bf16; 2048..2815 transpose Wqkv;
// 2816..3071 transpose Wout; 3072..3327 build RoPE cos/sin table
// ---------------------------------------------------------------------------
__global__ __launch_bounds__(256) void prep_fused(
    const float* __restrict__ x, const float* __restrict__ Wqkv,
    const float* __restrict__ Wout,
    unsigned short* __restrict__ xb, unsigned short* __restrict__ Wqkv_t,
    unsigned short* __restrict__ Wout_t, float2* __restrict__ rope_tab)
{
    __shared__ unsigned short tile[64][68];
    const int bid = blockIdx.x;
    const int tid = threadIdx.x;

    if (bid < 2048) {
        const int i = bid * 256 + tid;
        const float4 a = ((const float4*)x)[2 * i];
        const float4 b = ((const float4*)x)[2 * i + 1];
        u16x8 r;
        r[0] = f2bf(a.x); r[1] = f2bf(a.y); r[2] = f2bf(a.z); r[3] = f2bf(a.w);
        r[4] = f2bf(b.x); r[5] = f2bf(b.y); r[6] = f2bf(b.z); r[7] = f2bf(b.w);
        ((u16x8*)xb)[i] = r;
        return;
    }
    if (bid >= 3072) {
        const int idx = (bid - 3072) * 256 + tid;
        const int t = idx >> 5;
        const int d2 = idx & 31;
        const float inv_freq = exp2f(-(float)d2 * 0.41524101186092029f); // log2(1e4)/32
        float s, c;
        sincosf((float)t * inv_freq, &s, &c);
        rope_tab[idx] = make_float2(c, s);
        return;
    }

    const float* src;
    unsigned short* dst;
    int R, C, bx, by;
    if (bid < 2816) {
        const int id = bid - 2048;
        src = Wqkv; dst = Wqkv_t; R = DMODEL; C = 3 * DMODEL;
        bx = id % 48; by = id / 48;
    } else {
        const int id = bid - 2816;
        src = Wout; dst = Wout_t; R = DMODEL; C = DMODEL;
        bx = id % 16; by = id / 16;
    }
    const int tc0 = bx * 64;
    const int tr0 = by * 64;
    const int tx = tid & 63;
    const int ty = tid >> 6;
#pragma unroll
    for (int i = 0; i < 16; i++) {
        const int rr = i * 4 + ty;
        tile[tx][rr] = f2bf(src[(size_t)(tr0 + rr) * C + tc0 + tx]);
    }
    __syncthreads();
#pragma unroll
    for (int i = 0; i < 16; i++) {
        const int cc = i * 4 + ty;
        dst[(size_t)(tc0 + cc) * R + tr0 + tx] = tile[cc][tx];
    }
}

// ---------------------------------------------------------------------------
// Shared MFMA GEMM main loop, DOUBLE-BUFFERED, one barrier per K-slice.
// (Round-0 proven form — do not touch; see session notes: 8-phase x2 and
// counted-vmcnt 3-buf all lost their A/B. Latency hiding comes from
// 3 blocks/CU TLP at 76 VGPR; every rewrite broke that.)
// ---------------------------------------------------------------------------
__device__ __forceinline__ void mfma_gemm_loop_db(
    const unsigned short* __restrict__ A, const unsigned short* __restrict__ Bt,
    unsigned short* As, unsigned short* Bs,
    int m0, int n0, int K, f32x4 acc[4][4])
{
    const int tid  = threadIdx.x;
    const int wave = tid >> 6;
    const int lane = tid & 63;
    const int quad = lane >> 4;
    const int lc   = lane & 15;
    const int wr   = (wave >> 1) * 64;
    const int wc   = (wave & 1) * 64;

    const int c0    = wave * 2;
    const int srow0 = c0 * 16 + (lane >> 2);
    const int scol  = (lane & 3) * 8;

#pragma unroll
    for (int i = 0; i < 4; i++)
#pragma unroll
        for (int j = 0; j < 4; j++)
            acc[i][j] = (f32x4){0.f, 0.f, 0.f, 0.f};

    auto stage = [&](int kt, int buf) {
        const unsigned short* ga0 = A + (size_t)(m0 + srow0) * K + kt + scol;
        const unsigned short* ga1 = A + (size_t)(m0 + srow0 + 16) * K + kt + scol;
        const unsigned short* gb0 = Bt + (size_t)(n0 + srow0) * K + kt + scol;
        const unsigned short* gb1 = Bt + (size_t)(n0 + srow0 + 16) * K + kt + scol;
        unsigned short* as = As + buf * 4096;
        unsigned short* bs = Bs + buf * 4096;
        __builtin_amdgcn_global_load_lds((GUI*)ga0, (LUI*)(as + c0 * 512 + lane * 8), 16, 0, 0);
        __builtin_amdgcn_global_load_lds((GUI*)ga1, (LUI*)(as + (c0 + 1) * 512 + lane * 8), 16, 0, 0);
        __builtin_amdgcn_global_load_lds((GUI*)gb0, (LUI*)(bs + c0 * 512 + lane * 8), 16, 0, 0);
        __builtin_amdgcn_global_load_lds((GUI*)gb1, (LUI*)(bs + (c0 + 1) * 512 + lane * 8), 16, 0, 0);
    };

    stage(0, 0);
    const int nit = K >> 5;
    for (int it = 0; it < nit; ++it) {
        __syncthreads();
        if (it + 1 < nit) stage((it + 1) << 5, (it + 1) & 1);

        const unsigned short* as = As + (it & 1) * 4096;
        const unsigned short* bs = Bs + (it & 1) * 4096;
        s16x8 a[4], b[4];
#pragma unroll
        for (int mt = 0; mt < 4; mt++)
            a[mt] = *(const s16x8*)(as + (wr + mt * 16 + lc) * 32 + quad * 8);
#pragma unroll
        for (int nb = 0; nb < 4; nb++)
            b[nb] = *(const s16x8*)(bs + (wc + nb * 16 + lc) * 32 + quad * 8);
#pragma unroll
        for (int mt = 0; mt < 4; mt++)
#pragma unroll
            for (int nb = 0; nb < 4; nb++)
                acc[mt][nb] = __builtin_amdgcn_mfma_f32_16x16x32_bf16(a[mt], b[nb], acc[mt][nb], 0, 0, 0);
    }
}

// ---------------------------------------------------------------------------
// QKV GEMM (bf16 MFMA, dbuf) + RoPE (table lookup) + Q-scale + pack.
// 1-D grid 768, XCD-affine. (Round-0 proven version: ~48 us.)
// ---------------------------------------------------------------------------
__global__ __launch_bounds__(256) void gemm_qkv_rope_mfma(
    const unsigned short* __restrict__ xb, const unsigned short* __restrict__ Wt,
    const float2* __restrict__ rope_tab,
    unsigned short* __restrict__ Qb, unsigned short* __restrict__ Kb,
    unsigned short* __restrict__ Vb)
{
    __shared__ __align__(16) unsigned short As[2 * 128 * 32];
    __shared__ __align__(16) unsigned short Bs[2 * 128 * 32];

    const int id  = blockIdx.x;               // 0..767
    const int s   = id >> 3;                  // 0..95
    const int n0  = ((id & 7) * 3 + (s % 3)) * 128;
    const int m0  = (s / 3) * 128;
    f32x4 acc[4][4];
    mfma_gemm_loop_db(xb, Wt, As, Bs, m0, n0, DMODEL, acc);

    const int lane = threadIdx.x & 63;
    const int wave = threadIdx.x >> 6;
    const int quad = lane >> 4;
    const int lc   = lane & 15;
    const int wr   = (wave >> 1) * 64;
    const int wc   = (wave & 1) * 64;

    const int n_base = n0 + wc;
    const int part = n_base >> 10;       // 0=q 1=k 2=v, uniform per block
    unsigned short* dst = (part == 0) ? Qb : (part == 1 ? Kb : Vb);
    const float scale = (part == 0) ? 0.125f * 1.4426950408889634f : 1.0f;

#pragma unroll
    for (int nb = 0; nb < 4; nb++) {
        const int n = n_base + nb * 16 + lc;
        const int h = (n >> 6) & 15;
        const int d = n & 63;
        if (part == 2) {
#pragma unroll
            for (int mt = 0; mt < 4; mt++) {
                const int mb = m0 + wr + mt * 16 + quad * 4;
                const int bb = mb >> 11, t = mb & 2047;
                u16x4 pk;
                pk[0] = f2bf(acc[mt][nb][0]); pk[1] = f2bf(acc[mt][nb][1]);
                pk[2] = f2bf(acc[mt][nb][2]); pk[3] = f2bf(acc[mt][nb][3]);
                *(u16x4*)&dst[((size_t)(bb * NHEAD + h) * HDIM + d) * T_SEQ + t] = pk;
            }
        } else {
            const size_t hb = (size_t)h * T_SEQ * HDIM + d;
            const int d2 = d >> 1;
            const float ssign = (lc & 1) ? 1.f : -1.f;
#pragma unroll
            for (int mt = 0; mt < 4; mt++) {
                const int mb = m0 + wr + mt * 16 + quad * 4;
#pragma unroll
                for (int r = 0; r < 4; r++) {
                    const float val = acc[mt][nb][r];
                    const float prt = __shfl_xor(val, 1);
                    const int m = mb + r;
                    const int bb = m >> 11, t = m & 2047;
                    const float2 sc = rope_tab[t * 32 + d2];   // (cos, sin)
                    const float res = fmaf(prt, ssign * sc.y, val * sc.x) * scale;
                    dst[(size_t)bb * NHEAD * T_SEQ * HDIM + hb + (size_t)t * HDIM] = f2bf(res);
                }
            }
        }
    }
}

// ---------------------------------------------------------------------------
// Out-proj GEMM v2: 128x64 tile, grid 512 = 2 blocks/CU.
// ---------------------------------------------------------------------------
__global__ __launch_bounds__(256) void gemm_out_mfma(
    const unsigned short* __restrict__ A, const unsigned short* __restrict__ Bt,
    float* __restrict__ C, int N, int K)
{
    __shared__ __align__(16) unsigned short As[2 * 128 * 32];  // 16 KB
    __shared__ __align__(16) unsigned short Bs[2 * 64 * 32];   //  8 KB

    const int id = blockIdx.x;            // 0..511
    const int s  = id >> 3;               // 0..63
    const int n0 = ((id & 7) * 2 + (s & 1)) * 64;   // 16 n-blocks, XCD-affine
    const int m0 = (s >> 1) * 128;                  // 32 m-blocks

    const int tid  = threadIdx.x;
    const int wave = tid >> 6;
    const int lane = tid & 63;
    const int quad = lane >> 4;
    const int lc   = lane & 15;
    const int wr   = wave * 32;           // 4 waves stacked along M

    const int c0    = wave * 2;
    const int arow0 = c0 * 16 + (lane >> 2);        // A stage rows (128)
    const int brow0 = wave * 16 + (lane >> 2);      // B stage rows (64)
    const int scol  = (lane & 3) * 8;

    f32x4 acc[2][4];
#pragma unroll
    for (int i = 0; i < 2; i++)
#pragma unroll
        for (int j = 0; j < 4; j++)
            acc[i][j] = (f32x4){0.f, 0.f, 0.f, 0.f};

    auto stage = [&](int kt, int buf) {
        const unsigned short* ga0 = A + (size_t)(m0 + arow0) * K + kt + scol;
        const unsigned short* ga1 = A + (size_t)(m0 + arow0 + 16) * K + kt + scol;
        const unsigned short* gb0 = Bt + (size_t)(n0 + brow0) * K + kt + scol;
        unsigned short* as = As + buf * 4096;
        unsigned short* bs = Bs + buf * 2048;
        __builtin_amdgcn_global_load_lds((GUI*)ga0, (LUI*)(as + c0 * 512 + lane * 8), 16, 0, 0);
        __builtin_amdgcn_global_load_lds((GUI*)ga1, (LUI*)(as + (c0 + 1) * 512 + lane * 8), 16, 0, 0);
        __builtin_amdgcn_global_load_lds((GUI*)gb0, (LUI*)(bs + wave * 512 + lane * 8), 16, 0, 0);
    };

    stage(0, 0);
    const int nit = K >> 5;
    for (int it = 0; it < nit; ++it) {
        __syncthreads();
        if (it + 1 < nit) stage((it + 1) << 5, (it + 1) & 1);

        const unsigned short* as = As + (it & 1) * 4096;
        const unsigned short* bs = Bs + (it & 1) * 2048;
        s16x8 a[2], b[4];
#pragma unroll
        for (int mt = 0; mt < 2; mt++)
            a[mt] = *(const s16x8*)(as + (wr + mt * 16 + lc) * 32 + quad * 8);
#pragma unroll
        for (int nb = 0; nb < 4; nb++)
            b[nb] = *(const s16x8*)(bs + (nb * 16 + lc) * 32 + quad * 8);
#pragma unroll
        for (int mt = 0; mt < 2; mt++)
#pragma unroll
            for (int nb = 0; nb < 4; nb++)
                acc[mt][nb] = __builtin_amdgcn_mfma_f32_16x16x32_bf16(a[mt], b[nb], acc[mt][nb], 0, 0, 0);
    }

#pragma unroll
    for (int mt = 0; mt < 2; mt++) {
        const int mb = m0 + wr + mt * 16 + quad * 4;
#pragma unroll
        for (int r = 0; r < 4; r++) {
            float* row = C + (size_t)(mb + r) * N + n0;
#pragma unroll
            for (int nb = 0; nb < 4; nb++)
                row[nb * 16 + lc] = acc[mt][nb][r];
        }
    }
}

// ---------------------------------------------------------------------------
// MFMA causal flash attention v9: single-pass blocks on a 1024-wide grid
// (32 bh x 32 q-blocks), longest blocks dispatched first.
// (Best attn config of the session. v10's 128-row dual-pipeline superblock
// REGRESSED — it doubled the longest block's serial tile count 32->63; the
// makespan is bound by that diagonal-block critical path, not by per-tile
// overhead. Do not lengthen the critical path.)
// ---------------------------------------------------------------------------
__global__ __launch_bounds__(256, 3) void attn_mfma9(
    const unsigned short* __restrict__ Qb, const unsigned short* __restrict__ Kb,
    const unsigned short* __restrict__ Vtg, unsigned short* __restrict__ out)
{
    __shared__ __align__(16) unsigned short Ks[2][64 * 64];
    __shared__ __align__(16) unsigned short Vs[2][64 * 64];
    __shared__ __align__(16) unsigned short Ps[4][16 * 72];

    const int tid  = threadIdx.x;
    const int lane = tid & 63;
    const int wave = tid >> 6;           // 0..3
    const int quad = lane >> 4;
    const int lc   = lane & 15;
    const int rsw  = lc & 7;

    const int id   = blockIdx.x;             // 0..1023
    const int bh   = id & 31;                // head-slot; id%8==bh%8 -> XCD-affine
    const int qb   = 31 - (id >> 5);         // longest blocks first
    const int t0   = qb * 64;
    const int n_tiles = qb + 1;

    const size_t headK = (size_t)bh * T_SEQ * HDIM;   // Q,K: (BH,T,64)
    const size_t headV = (size_t)bh * HDIM * T_SEQ;   // Vt:  (BH,64,T)
    const int b = bh >> 4;
    const int h = bh & 15;

    const int c0   = wave * 2;
    const int krow = lane >> 3;
    const int d8sw = (lane & 7) ^ krow;
    unsigned short* pw = Ps[wave];

    s16x8 qf0, qf1;
    {
        const size_t qrow = headK + (size_t)(t0 + wave * 16 + lc) * HDIM;
        qf0 = *(const s16x8*)(Qb + qrow + quad * 8);
        qf1 = *(const s16x8*)(Qb + qrow + 32 + quad * 8);
    }

    f32x4 o[4];
    float m_i = -INFINITY, l_i = 0.f;
#pragma unroll
    for (int db = 0; db < 4; db++)
        o[db] = (f32x4){0.f, 0.f, 0.f, 0.f};

    auto stage = [&](int s0, int buf) {
        const unsigned short* gk0 = Kb  + headK + (size_t)(s0 + c0 * 8 + krow) * HDIM + d8sw * 8;
        const unsigned short* gk1 = Kb  + headK + (size_t)(s0 + c0 * 8 + 8 + krow) * HDIM + d8sw * 8;
        const unsigned short* gv0 = Vtg + headV + (size_t)(c0 * 8 + krow) * T_SEQ + s0 + d8sw * 8;
        const unsigned short* gv1 = Vtg + headV + (size_t)(c0 * 8 + 8 + krow) * T_SEQ + s0 + d8sw * 8;
        __builtin_amdgcn_global_load_lds((GUI*)gk0, (LUI*)(Ks[buf] + c0 * 512 + lane * 8), 16, 0, 0);
        __builtin_amdgcn_global_load_lds((GUI*)gk1, (LUI*)(Ks[buf] + (c0 + 1) * 512 + lane * 8), 16, 0, 0);
        __builtin_amdgcn_global_load_lds((GUI*)gv0, (LUI*)(Vs[buf] + c0 * 512 + lane * 8), 16, 0, 0);
        __builtin_amdgcn_global_load_lds((GUI*)gv1, (LUI*)(Vs[buf] + (c0 + 1) * 512 + lane * 8), 16, 0, 0);
    };

    stage(0, 0);

    for (int tile = 0; tile < n_tiles; ++tile) {
        const int s0 = tile * 64;
        const int buf = tile & 1;
        __syncthreads();
        if (tile + 1 < n_tiles) stage(s0 + 64, buf ^ 1);

        const unsigned short* ks = Ks[buf];
        const unsigned short* vs = Vs[buf];

        f32x4 st[4];
        __builtin_amdgcn_s_setprio(1);
#pragma unroll
        for (int kb = 0; kb < 4; kb++) {
            const s16x8 ka0 = *(const s16x8*)&ks[(kb * 16 + lc) * 64 + ((quad ^ rsw) * 8)];
            const s16x8 ka1 = *(const s16x8*)&ks[(kb * 16 + lc) * 64 + (((4 + quad) ^ rsw) * 8)];
            f32x4 z = (f32x4){0.f, 0.f, 0.f, 0.f};
            z = __builtin_amdgcn_mfma_f32_16x16x32_bf16(ka0, qf0, z, 0, 0, 0);
            z = __builtin_amdgcn_mfma_f32_16x16x32_bf16(ka1, qf1, z, 0, 0, 0);
            st[kb] = z;
        }
        __builtin_amdgcn_s_setprio(0);

        s16x8 va[4][2];
#pragma unroll
        for (int db = 0; db < 4; db++) {
            va[db][0] = *(const s16x8*)&vs[(db * 16 + lc) * 64 + ((quad ^ rsw) * 8)];
            va[db][1] = *(const s16x8*)&vs[(db * 16 + lc) * 64 + (((4 + quad) ^ rsw) * 8)];
        }

        if (tile == n_tiles - 1) {
            const int qrow = t0 + wave * 16 + lc;
#pragma unroll
            for (int kb = 0; kb < 4; kb++) {
                const int key = s0 + kb * 16 + quad * 4;
#pragma unroll
                for (int r = 0; r < 4; r++)
                    if (key + r > qrow) st[kb][r] = -INFINITY;
            }
        }

        // tile max: tree reduction
        float x0 = fmaxf(fmaxf(st[0][0], st[0][1]), st[0][2]);
        float x1 = fmaxf(fmaxf(st[0][3], st[1][0]), st[1][1]);
        float x2 = fmaxf(fmaxf(st[1][2], st[1][3]), st[2][0]);
        float x3 = fmaxf(fmaxf(st[2][1], st[2][2]), st[2][3]);
        float x4 = fmaxf(fmaxf(st[3][0], st[3][1]), st[3][2]);
        float mt = fmaxf(fmaxf(fmaxf(x0, x1), fmaxf(x2, x3)),
                         fmaxf(x4, st[3][3]));
        mt = fmaxf(mt, __shfl_xor(mt, 16));
        mt = fmaxf(mt, __shfl_xor(mt, 32));

        // T13 defer-max: skip rescale while tile max stays within THR=8
        if (!__all(mt <= m_i + 8.0f)) {
            const float mn = fmaxf(m_i, mt);
            const float alpha = __builtin_amdgcn_exp2f(m_i - mn);
            m_i = mn;
            l_i *= alpha;
#pragma unroll
            for (int db = 0; db < 4; db++) {
                o[db][0] *= alpha; o[db][1] *= alpha;
                o[db][2] *= alpha; o[db][3] *= alpha;
            }
        }

        float r0, r1, r2, r3;
#pragma unroll
        for (int kb = 0; kb < 4; kb++) {
            const float e0 = __builtin_amdgcn_exp2f(st[kb][0] - m_i);
            const float e1 = __builtin_amdgcn_exp2f(st[kb][1] - m_i);
            const float e2 = __builtin_amdgcn_exp2f(st[kb][2] - m_i);
            const float e3 = __builtin_amdgcn_exp2f(st[kb][3] - m_i);
            st[kb][0] = e0; st[kb][1] = e1; st[kb][2] = e2; st[kb][3] = e3;
            const float rp = (e0 + e1) + (e2 + e3);
            if (kb == 0) r0 = rp; else if (kb == 1) r1 = rp;
            else if (kb == 2) r2 = rp; else r3 = rp;
        }
        float rs = (r0 + r1) + (r2 + r3);
        rs += __shfl_xor(rs, 16);
        rs += __shfl_xor(rs, 32);
        l_i += rs;

#pragma unroll
        for (int kb = 0; kb < 4; kb++) {
            u32x2 pk;
            pk[0] = f2bf_pack2(st[kb][0], st[kb][1]);
            pk[1] = f2bf_pack2(st[kb][2], st[kb][3]);
            *(u32x2*)&pw[lc * 72 + kb * 16 + quad * 4] = pk;
        }
        const s16x8 pb0 = *(const s16x8*)&pw[lc * 72 + quad * 8];
        const s16x8 pb1 = *(const s16x8*)&pw[lc * 72 + 32 + quad * 8];
        __builtin_amdgcn_s_setprio(1);
#pragma unroll
        for (int db = 0; db < 4; db++) {
            o[db] = __builtin_amdgcn_mfma_f32_16x16x32_bf16(va[db][0], pb0, o[db], 0, 0, 0);
            o[db] = __builtin_amdgcn_mfma_f32_16x16x32_bf16(va[db][1], pb1, o[db], 0, 0, 0);
        }
        __builtin_amdgcn_s_setprio(0);
    }

    {
        const float inv_l = 1.f / l_i;
        const int t = t0 + wave * 16 + lc;
        unsigned short* orow = out + (size_t)(b * T_SEQ + t) * DMODEL + h * HDIM + quad * 4;
#pragma unroll
        for (int db = 0; db < 4; db++) {
            u32x2 pk;
            pk[0] = f2bf_pack2(o[db][0] * inv_l, o[db][1] * inv_l);
            pk[1] = f2bf_pack2(o[db][2] * inv_l, o[db][3] * inv_l);
            *(u32x2*)(orow + db * 16) = pk;
        }
    }
}

// ---------------------------------------------------------------------------
extern "C" void kernel_launch(void* const* d_in, const int* in_sizes, int n_in,
                              void* d_out, int out_size, void* d_ws, size_t ws_size,
                              hipStream_t stream)
{
    const float* x    = (const float*)d_in[0];   // (B,T,D) fp32
    const float* Wqkv = (const float*)d_in[1];   // (D,3D) fp32
    const float* Wout = (const float*)d_in[2];   // (D,D) fp32
    // d_in[3] attn_mask: causal triu(k=1), applied analytically.

    float* out = (float*)d_out;

    char* ws = (char*)d_ws;
    unsigned short* attnb  = (unsigned short*)(ws);               // (B,T,D) bf16, 8 MB
    unsigned short* Qb     = (unsigned short*)(ws + (8u  << 20)); // (B,H,T,64)
    unsigned short* Kb     = (unsigned short*)(ws + (16u << 20)); // (B,H,T,64)
    unsigned short* Vt     = (unsigned short*)(ws + (24u << 20)); // (B,H,64,T)
    unsigned short* xbuf   = (unsigned short*)(ws + (32u << 20)); // (M,K) bf16
    unsigned short* Wqkv_t = (unsigned short*)(ws + (40u << 20)); // (3D,D) bf16
    unsigned short* Wout_t = (unsigned short*)(ws + (46u << 20)); // (D,D) bf16
    float2*         ropeT  = (float2*)       (ws + (48u << 20)); // 2048x32 float2, 512 KB

    // 0) fused prep: convert x, transpose weights, build RoPE table
    prep_fused<<<dim3(3328), 256, 0, stream>>>(x, Wqkv, Wout, xbuf, Wqkv_t, Wout_t, ropeT);

    // 1) QKV MFMA GEMM (dbuf, XCD-affine) + RoPE table + scale + pack
    gemm_qkv_rope_mfma<<<dim3(768), 256, 0, stream>>>(xbuf, Wqkv_t, ropeT, Qb, Kb, Vt);

    // 2) MFMA causal flash attention v9 (single-pass, longest-first)
    attn_mfma9<<<dim3(1024), 256, 0, stream>>>(Qb, Kb, Vt, attnb);

    // 3) out = attnb @ Wout  (fp32 out, 128x64 tile, 2 blocks/CU)
    gemm_out_mfma<<<dim3(512), 256, 0, stream>>>(attnb, Wout_t, out, DMODEL, DMODEL);
}

// Round 9
// 190.407 us; speedup vs baseline: 1.0587x; 1.0282x over previous
//
#include <hip/hip_runtime.h>
#include <math.h>

#define BATCH   2
#define T_SEQ   2048
#define DMODEL  1024
#define NHEAD   16
#define HDIM    64

typedef short s16x8 __attribute__((ext_vector_type(8)));
typedef unsigned short u16x8 __attribute__((ext_vector_type(8)));
typedef unsigned short u16x4 __attribute__((ext_vector_type(4)));
typedef unsigned int u32x2 __attribute__((ext_vector_type(2)));
typedef float f32x4 __attribute__((ext_vector_type(4)));

typedef const unsigned int __attribute__((address_space(1))) GUI;
typedef unsigned int __attribute__((address_space(3))) LUI;

// fp32 -> bf16 round-to-nearest-even (bit pattern)
static __device__ __forceinline__ unsigned short f2bf(float f) {
    unsigned int u = __float_as_uint(f);
    u += 0x7fffu + ((u >> 16) & 1u);
    return (unsigned short)(u >> 16);
}

// two fp32 -> packed bf16x2 (round-half-up) via one v_perm_b32
static __device__ __forceinline__ unsigned int f2bf_pack2(float a, float b) {
    const unsigned int ua = __float_as_uint(a) + 0x8000u;
    const unsigned int ub = __float_as_uint(b) + 0x8000u;
    return __builtin_amdgcn_perm(ub, ua, 0x07060302u);
}

// ---------------------------------------------------------------------------
// Fused prep: blocks 0..2047 convert x -> bf16; 2048..2815 transpose Wqkv;
// 2816..3071 transpose Wout; 3072..3327 build RoPE cos/sin table
// ---------------------------------------------------------------------------
__global__ __launch_bounds__(256) void prep_fused(
    const float* __restrict__ x, const float* __restrict__ Wqkv,
    const float* __restrict__ Wout,
    unsigned short* __restrict__ xb, unsigned short* __restrict__ Wqkv_t,
    unsigned short* __restrict__ Wout_t, float2* __restrict__ rope_tab)
{
    __shared__ unsigned short tile[64][68];
    const int bid = blockIdx.x;
    const int tid = threadIdx.x;

    if (bid < 2048) {
        const int i = bid * 256 + tid;
        const float4 a = ((const float4*)x)[2 * i];
        const float4 b = ((const float4*)x)[2 * i + 1];
        u16x8 r;
        r[0] = f2bf(a.x); r[1] = f2bf(a.y); r[2] = f2bf(a.z); r[3] = f2bf(a.w);
        r[4] = f2bf(b.x); r[5] = f2bf(b.y); r[6] = f2bf(b.z); r[7] = f2bf(b.w);
        ((u16x8*)xb)[i] = r;
        return;
    }
    if (bid >= 3072) {
        const int idx = (bid - 3072) * 256 + tid;
        const int t = idx >> 5;
        const int d2 = idx & 31;
        const float inv_freq = exp2f(-(float)d2 * 0.41524101186092029f); // log2(1e4)/32
        float s, c;
        sincosf((float)t * inv_freq, &s, &c);
        rope_tab[idx] = make_float2(c, s);
        return;
    }

    const float* src;
    unsigned short* dst;
    int R, C, bx, by;
    if (bid < 2816) {
        const int id = bid - 2048;
        src = Wqkv; dst = Wqkv_t; R = DMODEL; C = 3 * DMODEL;
        bx = id % 48; by = id / 48;
    } else {
        const int id = bid - 2816;
        src = Wout; dst = Wout_t; R = DMODEL; C = DMODEL;
        bx = id % 16; by = id / 16;
    }
    const int tc0 = bx * 64;
    const int tr0 = by * 64;
    const int tx = tid & 63;
    const int ty = tid >> 6;
#pragma unroll
    for (int i = 0; i < 16; i++) {
        const int rr = i * 4 + ty;
        tile[tx][rr] = f2bf(src[(size_t)(tr0 + rr) * C + tc0 + tx]);
    }
    __syncthreads();
#pragma unroll
    for (int i = 0; i < 16; i++) {
        const int cc = i * 4 + ty;
        dst[(size_t)(tc0 + cc) * R + tr0 + tx] = tile[cc][tx];
    }
}

// ---------------------------------------------------------------------------
// Shared MFMA GEMM main loop, DOUBLE-BUFFERED, one barrier per K-slice.
// (Round-0 proven form — do not touch; see session notes.)
// ---------------------------------------------------------------------------
__device__ __forceinline__ void mfma_gemm_loop_db(
    const unsigned short* __restrict__ A, const unsigned short* __restrict__ Bt,
    unsigned short* As, unsigned short* Bs,
    int m0, int n0, int K, f32x4 acc[4][4])
{
    const int tid  = threadIdx.x;
    const int wave = tid >> 6;
    const int lane = tid & 63;
    const int quad = lane >> 4;
    const int lc   = lane & 15;
    const int wr   = (wave >> 1) * 64;
    const int wc   = (wave & 1) * 64;

    const int c0    = wave * 2;
    const int srow0 = c0 * 16 + (lane >> 2);
    const int scol  = (lane & 3) * 8;

#pragma unroll
    for (int i = 0; i < 4; i++)
#pragma unroll
        for (int j = 0; j < 4; j++)
            acc[i][j] = (f32x4){0.f, 0.f, 0.f, 0.f};

    auto stage = [&](int kt, int buf) {
        const unsigned short* ga0 = A + (size_t)(m0 + srow0) * K + kt + scol;
        const unsigned short* ga1 = A + (size_t)(m0 + srow0 + 16) * K + kt + scol;
        const unsigned short* gb0 = Bt + (size_t)(n0 + srow0) * K + kt + scol;
        const unsigned short* gb1 = Bt + (size_t)(n0 + srow0 + 16) * K + kt + scol;
        unsigned short* as = As + buf * 4096;
        unsigned short* bs = Bs + buf * 4096;
        __builtin_amdgcn_global_load_lds((GUI*)ga0, (LUI*)(as + c0 * 512 + lane * 8), 16, 0, 0);
        __builtin_amdgcn_global_load_lds((GUI*)ga1, (LUI*)(as + (c0 + 1) * 512 + lane * 8), 16, 0, 0);
        __builtin_amdgcn_global_load_lds((GUI*)gb0, (LUI*)(bs + c0 * 512 + lane * 8), 16, 0, 0);
        __builtin_amdgcn_global_load_lds((GUI*)gb1, (LUI*)(bs + (c0 + 1) * 512 + lane * 8), 16, 0, 0);
    };

    stage(0, 0);
    const int nit = K >> 5;
    for (int it = 0; it < nit; ++it) {
        __syncthreads();
        if (it + 1 < nit) stage((it + 1) << 5, (it + 1) & 1);

        const unsigned short* as = As + (it & 1) * 4096;
        const unsigned short* bs = Bs + (it & 1) * 4096;
        s16x8 a[4], b[4];
#pragma unroll
        for (int mt = 0; mt < 4; mt++)
            a[mt] = *(const s16x8*)(as + (wr + mt * 16 + lc) * 32 + quad * 8);
#pragma unroll
        for (int nb = 0; nb < 4; nb++)
            b[nb] = *(const s16x8*)(bs + (wc + nb * 16 + lc) * 32 + quad * 8);
#pragma unroll
        for (int mt = 0; mt < 4; mt++)
#pragma unroll
            for (int nb = 0; nb < 4; nb++)
                acc[mt][nb] = __builtin_amdgcn_mfma_f32_16x16x32_bf16(a[mt], b[nb], acc[mt][nb], 0, 0, 0);
    }
}

// ---------------------------------------------------------------------------
// QKV GEMM (bf16 MFMA, dbuf) + RoPE (table lookup) + Q-scale + pack.
// 1-D grid 768, XCD-affine. (Round-0 proven version: ~48 us.)
// ---------------------------------------------------------------------------
__global__ __launch_bounds__(256) void gemm_qkv_rope_mfma(
    const unsigned short* __restrict__ xb, const unsigned short* __restrict__ Wt,
    const float2* __restrict__ rope_tab,
    unsigned short* __restrict__ Qb, unsigned short* __restrict__ Kb,
    unsigned short* __restrict__ Vb)
{
    __shared__ __align__(16) unsigned short As[2 * 128 * 32];
    __shared__ __align__(16) unsigned short Bs[2 * 128 * 32];

    const int id  = blockIdx.x;               // 0..767
    const int s   = id >> 3;                  // 0..95
    const int n0  = ((id & 7) * 3 + (s % 3)) * 128;
    const int m0  = (s / 3) * 128;
    f32x4 acc[4][4];
    mfma_gemm_loop_db(xb, Wt, As, Bs, m0, n0, DMODEL, acc);

    const int lane = threadIdx.x & 63;
    const int wave = threadIdx.x >> 6;
    const int quad = lane >> 4;
    const int lc   = lane & 15;
    const int wr   = (wave >> 1) * 64;
    const int wc   = (wave & 1) * 64;

    const int n_base = n0 + wc;
    const int part = n_base >> 10;       // 0=q 1=k 2=v, uniform per block
    unsigned short* dst = (part == 0) ? Qb : (part == 1 ? Kb : Vb);
    const float scale = (part == 0) ? 0.125f * 1.4426950408889634f : 1.0f;

#pragma unroll
    for (int nb = 0; nb < 4; nb++) {
        const int n = n_base + nb * 16 + lc;
        const int h = (n >> 6) & 15;
        const int d = n & 63;
        if (part == 2) {
#pragma unroll
            for (int mt = 0; mt < 4; mt++) {
                const int mb = m0 + wr + mt * 16 + quad * 4;
                const int bb = mb >> 11, t = mb & 2047;
                u16x4 pk;
                pk[0] = f2bf(acc[mt][nb][0]); pk[1] = f2bf(acc[mt][nb][1]);
                pk[2] = f2bf(acc[mt][nb][2]); pk[3] = f2bf(acc[mt][nb][3]);
                *(u16x4*)&dst[((size_t)(bb * NHEAD + h) * HDIM + d) * T_SEQ + t] = pk;
            }
        } else {
            const size_t hb = (size_t)h * T_SEQ * HDIM + d;
            const int d2 = d >> 1;
            const float ssign = (lc & 1) ? 1.f : -1.f;
#pragma unroll
            for (int mt = 0; mt < 4; mt++) {
                const int mb = m0 + wr + mt * 16 + quad * 4;
#pragma unroll
                for (int r = 0; r < 4; r++) {
                    const float val = acc[mt][nb][r];
                    const float prt = __shfl_xor(val, 1);
                    const int m = mb + r;
                    const int bb = m >> 11, t = m & 2047;
                    const float2 sc = rope_tab[t * 32 + d2];   // (cos, sin)
                    const float res = fmaf(prt, ssign * sc.y, val * sc.x) * scale;
                    dst[(size_t)bb * NHEAD * T_SEQ * HDIM + hb + (size_t)t * HDIM] = f2bf(res);
                }
            }
        }
    }
}

// ---------------------------------------------------------------------------
// Out-proj GEMM v2: 128x64 tile, grid 512 = 2 blocks/CU.
// ---------------------------------------------------------------------------
__global__ __launch_bounds__(256) void gemm_out_mfma(
    const unsigned short* __restrict__ A, const unsigned short* __restrict__ Bt,
    float* __restrict__ C, int N, int K)
{
    __shared__ __align__(16) unsigned short As[2 * 128 * 32];  // 16 KB
    __shared__ __align__(16) unsigned short Bs[2 * 64 * 32];   //  8 KB

    const int id = blockIdx.x;            // 0..511
    const int s  = id >> 3;               // 0..63
    const int n0 = ((id & 7) * 2 + (s & 1)) * 64;   // 16 n-blocks, XCD-affine
    const int m0 = (s >> 1) * 128;                  // 32 m-blocks

    const int tid  = threadIdx.x;
    const int wave = tid >> 6;
    const int lane = tid & 63;
    const int quad = lane >> 4;
    const int lc   = lane & 15;
    const int wr   = wave * 32;           // 4 waves stacked along M

    const int c0    = wave * 2;
    const int arow0 = c0 * 16 + (lane >> 2);        // A stage rows (128)
    const int brow0 = wave * 16 + (lane >> 2);      // B stage rows (64)
    const int scol  = (lane & 3) * 8;

    f32x4 acc[2][4];
#pragma unroll
    for (int i = 0; i < 2; i++)
#pragma unroll
        for (int j = 0; j < 4; j++)
            acc[i][j] = (f32x4){0.f, 0.f, 0.f, 0.f};

    auto stage = [&](int kt, int buf) {
        const unsigned short* ga0 = A + (size_t)(m0 + arow0) * K + kt + scol;
        const unsigned short* ga1 = A + (size_t)(m0 + arow0 + 16) * K + kt + scol;
        const unsigned short* gb0 = Bt + (size_t)(n0 + brow0) * K + kt + scol;
        unsigned short* as = As + buf * 4096;
        unsigned short* bs = Bs + buf * 2048;
        __builtin_amdgcn_global_load_lds((GUI*)ga0, (LUI*)(as + c0 * 512 + lane * 8), 16, 0, 0);
        __builtin_amdgcn_global_load_lds((GUI*)ga1, (LUI*)(as + (c0 + 1) * 512 + lane * 8), 16, 0, 0);
        __builtin_amdgcn_global_load_lds((GUI*)gb0, (LUI*)(bs + wave * 512 + lane * 8), 16, 0, 0);
    };

    stage(0, 0);
    const int nit = K >> 5;
    for (int it = 0; it < nit; ++it) {
        __syncthreads();
        if (it + 1 < nit) stage((it + 1) << 5, (it + 1) & 1);

        const unsigned short* as = As + (it & 1) * 4096;
        const unsigned short* bs = Bs + (it & 1) * 2048;
        s16x8 a[2], b[4];
#pragma unroll
        for (int mt = 0; mt < 2; mt++)
            a[mt] = *(const s16x8*)(as + (wr + mt * 16 + lc) * 32 + quad * 8);
#pragma unroll
        for (int nb = 0; nb < 4; nb++)
            b[nb] = *(const s16x8*)(bs + (nb * 16 + lc) * 32 + quad * 8);
#pragma unroll
        for (int mt = 0; mt < 2; mt++)
#pragma unroll
            for (int nb = 0; nb < 4; nb++)
                acc[mt][nb] = __builtin_amdgcn_mfma_f32_16x16x32_bf16(a[mt], b[nb], acc[mt][nb], 0, 0, 0);
    }

#pragma unroll
    for (int mt = 0; mt < 2; mt++) {
        const int mb = m0 + wr + mt * 16 + quad * 4;
#pragma unroll
        for (int r = 0; r < 4; r++) {
            float* row = C + (size_t)(mb + r) * N + n0;
#pragma unroll
            for (int nb = 0; nb < 4; nb++)
                row[nb * 16 + lc] = acc[mt][nb][r];
        }
    }
}

// ---------------------------------------------------------------------------
// MFMA causal flash attention v11: v9's grid/staging/barrier schedule kept
// BYTE-IDENTICAL (64-key stage cadence, dbuf, 1024-grid longest-first,
// 3 blocks/CU), but the SOFTMAX is regrouped to once per 128 keys: each
// loop iteration runs two sub-tiles (lo=buf0, hi=buf1) collecting st/va,
// then ONE combined max/exp/rescale/l-update + pack + 16 PV MFMAs.
// Mechanism: the per-tile fixed serial cost F (max tree + 4 shfl_xor at
// ~60cyc latency + defer-check + rescale + l-update, ~300-500 cyc) is paid
// per softmax, not per key — halving softmax count saves ~33 pairs/CU x
// ~400 cyc ~= 5-7 us. Critical path NOT lengthened (v10 lesson).
// Odd tile counts peel a single 64-key tail using the old path.
// ---------------------------------------------------------------------------
__global__ __launch_bounds__(256, 3) void attn_mfma11(
    const unsigned short* __restrict__ Qb, const unsigned short* __restrict__ Kb,
    const unsigned short* __restrict__ Vtg, unsigned short* __restrict__ out)
{
    __shared__ __align__(16) unsigned short Ks[2][64 * 64];
    __shared__ __align__(16) unsigned short Vs[2][64 * 64];
    __shared__ __align__(16) unsigned short Ps[8][16 * 72];   // lo: [wave], hi: [wave+4]

    const int tid  = threadIdx.x;
    const int lane = tid & 63;
    const int wave = tid >> 6;           // 0..3
    const int quad = lane >> 4;
    const int lc   = lane & 15;
    const int rsw  = lc & 7;

    const int id   = blockIdx.x;             // 0..1023
    const int bh   = id & 31;                // head-slot; id%8==bh%8 -> XCD-affine
    const int qb   = 31 - (id >> 5);         // longest blocks first
    const int t0   = qb * 64;
    const int n_tiles = qb + 1;

    const size_t headK = (size_t)bh * T_SEQ * HDIM;   // Q,K: (BH,T,64)
    const size_t headV = (size_t)bh * HDIM * T_SEQ;   // Vt:  (BH,64,T)
    const int b = bh >> 4;
    const int h = bh & 15;

    const int c0   = wave * 2;
    const int krow = lane >> 3;
    const int d8sw = (lane & 7) ^ krow;
    unsigned short* pwl = Ps[wave];
    unsigned short* pwh = Ps[wave + 4];

    s16x8 qf0, qf1;
    {
        const size_t qrow = headK + (size_t)(t0 + wave * 16 + lc) * HDIM;
        qf0 = *(const s16x8*)(Qb + qrow + quad * 8);
        qf1 = *(const s16x8*)(Qb + qrow + 32 + quad * 8);
    }

    f32x4 o[4];
    float m_i = -INFINITY, l_i = 0.f;
#pragma unroll
    for (int db = 0; db < 4; db++)
        o[db] = (f32x4){0.f, 0.f, 0.f, 0.f};

    auto stage = [&](int s0, int buf) {
        const unsigned short* gk0 = Kb  + headK + (size_t)(s0 + c0 * 8 + krow) * HDIM + d8sw * 8;
        const unsigned short* gk1 = Kb  + headK + (size_t)(s0 + c0 * 8 + 8 + krow) * HDIM + d8sw * 8;
        const unsigned short* gv0 = Vtg + headV + (size_t)(c0 * 8 + krow) * T_SEQ + s0 + d8sw * 8;
        const unsigned short* gv1 = Vtg + headV + (size_t)(c0 * 8 + 8 + krow) * T_SEQ + s0 + d8sw * 8;
        __builtin_amdgcn_global_load_lds((GUI*)gk0, (LUI*)(Ks[buf] + c0 * 512 + lane * 8), 16, 0, 0);
        __builtin_amdgcn_global_load_lds((GUI*)gk1, (LUI*)(Ks[buf] + (c0 + 1) * 512 + lane * 8), 16, 0, 0);
        __builtin_amdgcn_global_load_lds((GUI*)gv0, (LUI*)(Vs[buf] + c0 * 512 + lane * 8), 16, 0, 0);
        __builtin_amdgcn_global_load_lds((GUI*)gv1, (LUI*)(Vs[buf] + (c0 + 1) * 512 + lane * 8), 16, 0, 0);
    };

    // QK^T of one 64-key sub-tile from Ks[buf] into st
    auto qk_tile = [&](const unsigned short* ks, f32x4 st[4]) {
        __builtin_amdgcn_s_setprio(1);
#pragma unroll
        for (int kb = 0; kb < 4; kb++) {
            const s16x8 ka0 = *(const s16x8*)&ks[(kb * 16 + lc) * 64 + ((quad ^ rsw) * 8)];
            const s16x8 ka1 = *(const s16x8*)&ks[(kb * 16 + lc) * 64 + (((4 + quad) ^ rsw) * 8)];
            f32x4 z = (f32x4){0.f, 0.f, 0.f, 0.f};
            z = __builtin_amdgcn_mfma_f32_16x16x32_bf16(ka0, qf0, z, 0, 0, 0);
            z = __builtin_amdgcn_mfma_f32_16x16x32_bf16(ka1, qf1, z, 0, 0, 0);
            st[kb] = z;
        }
        __builtin_amdgcn_s_setprio(0);
    };

    auto load_va = [&](const unsigned short* vs, s16x8 va[4][2]) {
#pragma unroll
        for (int db = 0; db < 4; db++) {
            va[db][0] = *(const s16x8*)&vs[(db * 16 + lc) * 64 + ((quad ^ rsw) * 8)];
            va[db][1] = *(const s16x8*)&vs[(db * 16 + lc) * 64 + (((4 + quad) ^ rsw) * 8)];
        }
    };

    auto mask_tile = [&](f32x4 st[4], int s0) {
        const int qrow = t0 + wave * 16 + lc;
#pragma unroll
        for (int kb = 0; kb < 4; kb++) {
            const int key = s0 + kb * 16 + quad * 4;
#pragma unroll
            for (int r = 0; r < 4; r++)
                if (key + r > qrow) st[kb][r] = -INFINITY;
        }
    };

    auto tile_max16 = [&](const f32x4 st[4]) -> float {
        float x0 = fmaxf(fmaxf(st[0][0], st[0][1]), st[0][2]);
        float x1 = fmaxf(fmaxf(st[0][3], st[1][0]), st[1][1]);
        float x2 = fmaxf(fmaxf(st[1][2], st[1][3]), st[2][0]);
        float x3 = fmaxf(fmaxf(st[2][1], st[2][2]), st[2][3]);
        float x4 = fmaxf(fmaxf(st[3][0], st[3][1]), st[3][2]);
        return fmaxf(fmaxf(fmaxf(x0, x1), fmaxf(x2, x3)),
                     fmaxf(x4, st[3][3]));
    };

    const int npairs = n_tiles >> 1;
    stage(0, 0);

    // ---- pair loop: two 64-key sub-tiles, ONE softmax per 128 keys
    for (int p = 0; p < npairs; ++p) {
        const int tlo = 2 * p;
        // sub-tile lo (buf 0)
        __syncthreads();
        if (tlo + 1 < n_tiles) stage((tlo + 1) * 64, 1);
        f32x4 stl[4], sth[4];
        qk_tile(Ks[0], stl);
        s16x8 val[4][2], vah[4][2];
        load_va(Vs[0], val);

        // sub-tile hi (buf 1)
        __syncthreads();
        if (tlo + 2 < n_tiles) stage((tlo + 2) * 64, 0);
        qk_tile(Ks[1], sth);
        load_va(Vs[1], vah);
        if (tlo + 2 == n_tiles) mask_tile(sth, (tlo + 1) * 64);  // hi is diag

        // ---- combined 128-key softmax (F paid once)
        float mt = fmaxf(tile_max16(stl), tile_max16(sth));
        mt = fmaxf(mt, __shfl_xor(mt, 16));
        mt = fmaxf(mt, __shfl_xor(mt, 32));

        if (!__all(mt <= m_i + 8.0f)) {     // T13 defer-max, THR=8 (log2)
            const float mn = fmaxf(m_i, mt);
            const float alpha = __builtin_amdgcn_exp2f(m_i - mn);
            m_i = mn;
            l_i *= alpha;
#pragma unroll
            for (int db = 0; db < 4; db++) {
                o[db][0] *= alpha; o[db][1] *= alpha;
                o[db][2] *= alpha; o[db][3] *= alpha;
            }
        }

        float rs = 0.f;
#pragma unroll
        for (int kb = 0; kb < 4; kb++) {
            const float l0 = __builtin_amdgcn_exp2f(stl[kb][0] - m_i);
            const float h0 = __builtin_amdgcn_exp2f(sth[kb][0] - m_i);
            const float l1 = __builtin_amdgcn_exp2f(stl[kb][1] - m_i);
            const float h1 = __builtin_amdgcn_exp2f(sth[kb][1] - m_i);
            const float l2 = __builtin_amdgcn_exp2f(stl[kb][2] - m_i);
            const float h2 = __builtin_amdgcn_exp2f(sth[kb][2] - m_i);
            const float l3 = __builtin_amdgcn_exp2f(stl[kb][3] - m_i);
            const float h3 = __builtin_amdgcn_exp2f(sth[kb][3] - m_i);
            stl[kb][0] = l0; stl[kb][1] = l1; stl[kb][2] = l2; stl[kb][3] = l3;
            sth[kb][0] = h0; sth[kb][1] = h1; sth[kb][2] = h2; sth[kb][3] = h3;
            rs += ((l0 + l1) + (l2 + l3)) + ((h0 + h1) + (h2 + h3));
        }
        rs += __shfl_xor(rs, 16);
        rs += __shfl_xor(rs, 32);
        l_i += rs;

        // pack both halves -> P LDS (disjoint per-wave buffers)
#pragma unroll
        for (int kb = 0; kb < 4; kb++) {
            u32x2 pkl, pkh;
            pkl[0] = f2bf_pack2(stl[kb][0], stl[kb][1]);
            pkl[1] = f2bf_pack2(stl[kb][2], stl[kb][3]);
            pkh[0] = f2bf_pack2(sth[kb][0], sth[kb][1]);
            pkh[1] = f2bf_pack2(sth[kb][2], sth[kb][3]);
            *(u32x2*)&pwl[lc * 72 + kb * 16 + quad * 4] = pkl;
            *(u32x2*)&pwh[lc * 72 + kb * 16 + quad * 4] = pkh;
        }
        const s16x8 pb0l = *(const s16x8*)&pwl[lc * 72 + quad * 8];
        const s16x8 pb1l = *(const s16x8*)&pwl[lc * 72 + 32 + quad * 8];
        const s16x8 pb0h = *(const s16x8*)&pwh[lc * 72 + quad * 8];
        const s16x8 pb1h = *(const s16x8*)&pwh[lc * 72 + 32 + quad * 8];
        __builtin_amdgcn_s_setprio(1);
#pragma unroll
        for (int db = 0; db < 4; db++) {
            o[db] = __builtin_amdgcn_mfma_f32_16x16x32_bf16(val[db][0], pb0l, o[db], 0, 0, 0);
            o[db] = __builtin_amdgcn_mfma_f32_16x16x32_bf16(val[db][1], pb1l, o[db], 0, 0, 0);
            o[db] = __builtin_amdgcn_mfma_f32_16x16x32_bf16(vah[db][0], pb0h, o[db], 0, 0, 0);
            o[db] = __builtin_amdgcn_mfma_f32_16x16x32_bf16(vah[db][1], pb1h, o[db], 0, 0, 0);
        }
        __builtin_amdgcn_s_setprio(0);
    }

    // ---- odd tail: single 64-key tile (always the diagonal, buf 0)
    if (n_tiles & 1) {
        const int tt = n_tiles - 1;
        __syncthreads();
        f32x4 st[4];
        qk_tile(Ks[0], st);
        s16x8 va[4][2];
        load_va(Vs[0], va);
        mask_tile(st, tt * 64);

        float mt = tile_max16(st);
        mt = fmaxf(mt, __shfl_xor(mt, 16));
        mt = fmaxf(mt, __shfl_xor(mt, 32));

        if (!__all(mt <= m_i + 8.0f)) {
            const float mn = fmaxf(m_i, mt);
            const float alpha = __builtin_amdgcn_exp2f(m_i - mn);
            m_i = mn;
            l_i *= alpha;
#pragma unroll
            for (int db = 0; db < 4; db++) {
                o[db][0] *= alpha; o[db][1] *= alpha;
                o[db][2] *= alpha; o[db][3] *= alpha;
            }
        }

        float rs = 0.f;
#pragma unroll
        for (int kb = 0; kb < 4; kb++) {
            const float e0 = __builtin_amdgcn_exp2f(st[kb][0] - m_i);
            const float e1 = __builtin_amdgcn_exp2f(st[kb][1] - m_i);
            const float e2 = __builtin_amdgcn_exp2f(st[kb][2] - m_i);
            const float e3 = __builtin_amdgcn_exp2f(st[kb][3] - m_i);
            st[kb][0] = e0; st[kb][1] = e1; st[kb][2] = e2; st[kb][3] = e3;
            rs += (e0 + e1) + (e2 + e3);
        }
        rs += __shfl_xor(rs, 16);
        rs += __shfl_xor(rs, 32);
        l_i += rs;

#pragma unroll
        for (int kb = 0; kb < 4; kb++) {
            u32x2 pk;
            pk[0] = f2bf_pack2(st[kb][0], st[kb][1]);
            pk[1] = f2bf_pack2(st[kb][2], st[kb][3]);
            *(u32x2*)&pwl[lc * 72 + kb * 16 + quad * 4] = pk;
        }
        const s16x8 pb0 = *(const s16x8*)&pwl[lc * 72 + quad * 8];
        const s16x8 pb1 = *(const s16x8*)&pwl[lc * 72 + 32 + quad * 8];
        __builtin_amdgcn_s_setprio(1);
#pragma unroll
        for (int db = 0; db < 4; db++) {
            o[db] = __builtin_amdgcn_mfma_f32_16x16x32_bf16(va[db][0], pb0, o[db], 0, 0, 0);
            o[db] = __builtin_amdgcn_mfma_f32_16x16x32_bf16(va[db][1], pb1, o[db], 0, 0, 0);
        }
        __builtin_amdgcn_s_setprio(0);
    }

    {
        const float inv_l = 1.f / l_i;
        const int t = t0 + wave * 16 + lc;
        unsigned short* orow = out + (size_t)(b * T_SEQ + t) * DMODEL + h * HDIM + quad * 4;
#pragma unroll
        for (int db = 0; db < 4; db++) {
            u32x2 pk;
            pk[0] = f2bf_pack2(o[db][0] * inv_l, o[db][1] * inv_l);
            pk[1] = f2bf_pack2(o[db][2] * inv_l, o[db][3] * inv_l);
            *(u32x2*)(orow + db * 16) = pk;
        }
    }
}

// ---------------------------------------------------------------------------
extern "C" void kernel_launch(void* const* d_in, const int* in_sizes, int n_in,
                              void* d_out, int out_size, void* d_ws, size_t ws_size,
                              hipStream_t stream)
{
    const float* x    = (const float*)d_in[0];   // (B,T,D) fp32
    const float* Wqkv = (const float*)d_in[1];   // (D,3D) fp32
    const float* Wout = (const float*)d_in[2];   // (D,D) fp32
    // d_in[3] attn_mask: causal triu(k=1), applied analytically.

    float* out = (float*)d_out;

    char* ws = (char*)d_ws;
    unsigned short* attnb  = (unsigned short*)(ws);               // (B,T,D) bf16, 8 MB
    unsigned short* Qb     = (unsigned short*)(ws + (8u  << 20)); // (B,H,T,64)
    unsigned short* Kb     = (unsigned short*)(ws + (16u << 20)); // (B,H,T,64)
    unsigned short* Vt     = (unsigned short*)(ws + (24u << 20)); // (B,H,64,T)
    unsigned short* xbuf   = (unsigned short*)(ws + (32u << 20)); // (M,K) bf16
    unsigned short* Wqkv_t = (unsigned short*)(ws + (40u << 20)); // (3D,D) bf16
    unsigned short* Wout_t = (unsigned short*)(ws + (46u << 20)); // (D,D) bf16
    float2*         ropeT  = (float2*)       (ws + (48u << 20)); // 2048x32 float2, 512 KB

    // 0) fused prep: convert x, transpose weights, build RoPE table
    prep_fused<<<dim3(3328), 256, 0, stream>>>(x, Wqkv, Wout, xbuf, Wqkv_t, Wout_t, ropeT);

    // 1) QKV MFMA GEMM (dbuf, XCD-affine) + RoPE table + scale + pack
    gemm_qkv_rope_mfma<<<dim3(768), 256, 0, stream>>>(xbuf, Wqkv_t, ropeT, Qb, Kb, Vt);

    // 2) MFMA causal flash attention v11 (paired-tile softmax, longest-first)
    attn_mfma11<<<dim3(1024), 256, 0, stream>>>(Qb, Kb, Vt, attnb);

    // 3) out = attnb @ Wout  (fp32 out, 128x64 tile, 2 blocks/CU)
    gemm_out_mfma<<<dim3(512), 256, 0, stream>>>(attnb, Wout_t, out, DMODEL, DMODEL);
}

// Round 10
// 187.728 us; speedup vs baseline: 1.0738x; 1.0143x over previous
//
#include <hip/hip_runtime.h>
#include <math.h>

#define BATCH   2
#define T_SEQ   2048
#define DMODEL  1024
#define NHEAD   16
#define HDIM    64

typedef short s16x8 __attribute__((ext_vector_type(8)));
typedef unsigned short u16x8 __attribute__((ext_vector_type(8)));
typedef unsigned short u16x4 __attribute__((ext_vector_type(4)));
typedef unsigned int u32x2 __attribute__((ext_vector_type(2)));
typedef float f32x4 __attribute__((ext_vector_type(4)));

typedef const unsigned int __attribute__((address_space(1))) GUI;
typedef unsigned int __attribute__((address_space(3))) LUI;

// fp32 -> bf16 round-to-nearest-even (bit pattern)
static __device__ __forceinline__ unsigned short f2bf(float f) {
    unsigned int u = __float_as_uint(f);
    u += 0x7fffu + ((u >> 16) & 1u);
    return (unsigned short)(u >> 16);
}

// two fp32 -> packed bf16x2 (round-half-up) via one v_perm_b32
static __device__ __forceinline__ unsigned int f2bf_pack2(float a, float b) {
    const unsigned int ua = __float_as_uint(a) + 0x8000u;
    const unsigned int ub = __float_as_uint(b) + 0x8000u;
    return __builtin_amdgcn_perm(ub, ua, 0x07060302u);
}

// ---------------------------------------------------------------------------
// Fused prep: blocks 0..2047 convert x -> bf16; 2048..2815 transpose Wqkv;
// 2816..3071 transpose Wout; 3072..3327 build RoPE cos/sin table
// ---------------------------------------------------------------------------
__global__ __launch_bounds__(256) void prep_fused(
    const float* __restrict__ x, const float* __restrict__ Wqkv,
    const float* __restrict__ Wout,
    unsigned short* __restrict__ xb, unsigned short* __restrict__ Wqkv_t,
    unsigned short* __restrict__ Wout_t, float2* __restrict__ rope_tab)
{
    __shared__ unsigned short tile[64][68];
    const int bid = blockIdx.x;
    const int tid = threadIdx.x;

    if (bid < 2048) {
        const int i = bid * 256 + tid;
        const float4 a = ((const float4*)x)[2 * i];
        const float4 b = ((const float4*)x)[2 * i + 1];
        u16x8 r;
        r[0] = f2bf(a.x); r[1] = f2bf(a.y); r[2] = f2bf(a.z); r[3] = f2bf(a.w);
        r[4] = f2bf(b.x); r[5] = f2bf(b.y); r[6] = f2bf(b.z); r[7] = f2bf(b.w);
        ((u16x8*)xb)[i] = r;
        return;
    }
    if (bid >= 3072) {
        const int idx = (bid - 3072) * 256 + tid;
        const int t = idx >> 5;
        const int d2 = idx & 31;
        const float inv_freq = exp2f(-(float)d2 * 0.41524101186092029f); // log2(1e4)/32
        float s, c;
        sincosf((float)t * inv_freq, &s, &c);
        rope_tab[idx] = make_float2(c, s);
        return;
    }

    const float* src;
    unsigned short* dst;
    int R, C, bx, by;
    if (bid < 2816) {
        const int id = bid - 2048;
        src = Wqkv; dst = Wqkv_t; R = DMODEL; C = 3 * DMODEL;
        bx = id % 48; by = id / 48;
    } else {
        const int id = bid - 2816;
        src = Wout; dst = Wout_t; R = DMODEL; C = DMODEL;
        bx = id % 16; by = id / 16;
    }
    const int tc0 = bx * 64;
    const int tr0 = by * 64;
    const int tx = tid & 63;
    const int ty = tid >> 6;
#pragma unroll
    for (int i = 0; i < 16; i++) {
        const int rr = i * 4 + ty;
        tile[tx][rr] = f2bf(src[(size_t)(tr0 + rr) * C + tc0 + tx]);
    }
    __syncthreads();
#pragma unroll
    for (int i = 0; i < 16; i++) {
        const int cc = i * 4 + ty;
        dst[(size_t)(tc0 + cc) * R + tr0 + tx] = tile[cc][tx];
    }
}

// ---------------------------------------------------------------------------
// Shared MFMA GEMM main loop, DOUBLE-BUFFERED, one barrier per K-slice.
// (Round-0 proven form — do not touch; see session notes.)
// ---------------------------------------------------------------------------
__device__ __forceinline__ void mfma_gemm_loop_db(
    const unsigned short* __restrict__ A, const unsigned short* __restrict__ Bt,
    unsigned short* As, unsigned short* Bs,
    int m0, int n0, int K, f32x4 acc[4][4])
{
    const int tid  = threadIdx.x;
    const int wave = tid >> 6;
    const int lane = tid & 63;
    const int quad = lane >> 4;
    const int lc   = lane & 15;
    const int wr   = (wave >> 1) * 64;
    const int wc   = (wave & 1) * 64;

    const int c0    = wave * 2;
    const int srow0 = c0 * 16 + (lane >> 2);
    const int scol  = (lane & 3) * 8;

#pragma unroll
    for (int i = 0; i < 4; i++)
#pragma unroll
        for (int j = 0; j < 4; j++)
            acc[i][j] = (f32x4){0.f, 0.f, 0.f, 0.f};

    auto stage = [&](int kt, int buf) {
        const unsigned short* ga0 = A + (size_t)(m0 + srow0) * K + kt + scol;
        const unsigned short* ga1 = A + (size_t)(m0 + srow0 + 16) * K + kt + scol;
        const unsigned short* gb0 = Bt + (size_t)(n0 + srow0) * K + kt + scol;
        const unsigned short* gb1 = Bt + (size_t)(n0 + srow0 + 16) * K + kt + scol;
        unsigned short* as = As + buf * 4096;
        unsigned short* bs = Bs + buf * 4096;
        __builtin_amdgcn_global_load_lds((GUI*)ga0, (LUI*)(as + c0 * 512 + lane * 8), 16, 0, 0);
        __builtin_amdgcn_global_load_lds((GUI*)ga1, (LUI*)(as + (c0 + 1) * 512 + lane * 8), 16, 0, 0);
        __builtin_amdgcn_global_load_lds((GUI*)gb0, (LUI*)(bs + c0 * 512 + lane * 8), 16, 0, 0);
        __builtin_amdgcn_global_load_lds((GUI*)gb1, (LUI*)(bs + (c0 + 1) * 512 + lane * 8), 16, 0, 0);
    };

    stage(0, 0);
    const int nit = K >> 5;
    for (int it = 0; it < nit; ++it) {
        __syncthreads();
        if (it + 1 < nit) stage((it + 1) << 5, (it + 1) & 1);

        const unsigned short* as = As + (it & 1) * 4096;
        const unsigned short* bs = Bs + (it & 1) * 4096;
        s16x8 a[4], b[4];
#pragma unroll
        for (int mt = 0; mt < 4; mt++)
            a[mt] = *(const s16x8*)(as + (wr + mt * 16 + lc) * 32 + quad * 8);
#pragma unroll
        for (int nb = 0; nb < 4; nb++)
            b[nb] = *(const s16x8*)(bs + (wc + nb * 16 + lc) * 32 + quad * 8);
#pragma unroll
        for (int mt = 0; mt < 4; mt++)
#pragma unroll
            for (int nb = 0; nb < 4; nb++)
                acc[mt][nb] = __builtin_amdgcn_mfma_f32_16x16x32_bf16(a[mt], b[nb], acc[mt][nb], 0, 0, 0);
    }
}

// ---------------------------------------------------------------------------
// QKV GEMM (bf16 MFMA, dbuf) + RoPE (table lookup) + Q-scale + pack.
// 1-D grid 768, XCD-affine. (Round-0 proven version: ~48 us.)
// ---------------------------------------------------------------------------
__global__ __launch_bounds__(256) void gemm_qkv_rope_mfma(
    const unsigned short* __restrict__ xb, const unsigned short* __restrict__ Wt,
    const float2* __restrict__ rope_tab,
    unsigned short* __restrict__ Qb, unsigned short* __restrict__ Kb,
    unsigned short* __restrict__ Vb)
{
    __shared__ __align__(16) unsigned short As[2 * 128 * 32];
    __shared__ __align__(16) unsigned short Bs[2 * 128 * 32];

    const int id  = blockIdx.x;               // 0..767
    const int s   = id >> 3;                  // 0..95
    const int n0  = ((id & 7) * 3 + (s % 3)) * 128;
    const int m0  = (s / 3) * 128;
    f32x4 acc[4][4];
    mfma_gemm_loop_db(xb, Wt, As, Bs, m0, n0, DMODEL, acc);

    const int lane = threadIdx.x & 63;
    const int wave = threadIdx.x >> 6;
    const int quad = lane >> 4;
    const int lc   = lane & 15;
    const int wr   = (wave >> 1) * 64;
    const int wc   = (wave & 1) * 64;

    const int n_base = n0 + wc;
    const int part = n_base >> 10;       // 0=q 1=k 2=v, uniform per block
    unsigned short* dst = (part == 0) ? Qb : (part == 1 ? Kb : Vb);
    const float scale = (part == 0) ? 0.125f * 1.4426950408889634f : 1.0f;

#pragma unroll
    for (int nb = 0; nb < 4; nb++) {
        const int n = n_base + nb * 16 + lc;
        const int h = (n >> 6) & 15;
        const int d = n & 63;
        if (part == 2) {
#pragma unroll
            for (int mt = 0; mt < 4; mt++) {
                const int mb = m0 + wr + mt * 16 + quad * 4;
                const int bb = mb >> 11, t = mb & 2047;
                u16x4 pk;
                pk[0] = f2bf(acc[mt][nb][0]); pk[1] = f2bf(acc[mt][nb][1]);
                pk[2] = f2bf(acc[mt][nb][2]); pk[3] = f2bf(acc[mt][nb][3]);
                *(u16x4*)&dst[((size_t)(bb * NHEAD + h) * HDIM + d) * T_SEQ + t] = pk;
            }
        } else {
            const size_t hb = (size_t)h * T_SEQ * HDIM + d;
            const int d2 = d >> 1;
            const float ssign = (lc & 1) ? 1.f : -1.f;
#pragma unroll
            for (int mt = 0; mt < 4; mt++) {
                const int mb = m0 + wr + mt * 16 + quad * 4;
#pragma unroll
                for (int r = 0; r < 4; r++) {
                    const float val = acc[mt][nb][r];
                    const float prt = __shfl_xor(val, 1);
                    const int m = mb + r;
                    const int bb = m >> 11, t = m & 2047;
                    const float2 sc = rope_tab[t * 32 + d2];   // (cos, sin)
                    const float res = fmaf(prt, ssign * sc.y, val * sc.x) * scale;
                    dst[(size_t)bb * NHEAD * T_SEQ * HDIM + hb + (size_t)t * HDIM] = f2bf(res);
                }
            }
        }
    }
}

// ---------------------------------------------------------------------------
// Out-proj GEMM v2: 128x64 tile, grid 512 = 2 blocks/CU.
// ---------------------------------------------------------------------------
__global__ __launch_bounds__(256) void gemm_out_mfma(
    const unsigned short* __restrict__ A, const unsigned short* __restrict__ Bt,
    float* __restrict__ C, int N, int K)
{
    __shared__ __align__(16) unsigned short As[2 * 128 * 32];  // 16 KB
    __shared__ __align__(16) unsigned short Bs[2 * 64 * 32];   //  8 KB

    const int id = blockIdx.x;            // 0..511
    const int s  = id >> 3;               // 0..63
    const int n0 = ((id & 7) * 2 + (s & 1)) * 64;   // 16 n-blocks, XCD-affine
    const int m0 = (s >> 1) * 128;                  // 32 m-blocks

    const int tid  = threadIdx.x;
    const int wave = tid >> 6;
    const int lane = tid & 63;
    const int quad = lane >> 4;
    const int lc   = lane & 15;
    const int wr   = wave * 32;           // 4 waves stacked along M

    const int c0    = wave * 2;
    const int arow0 = c0 * 16 + (lane >> 2);        // A stage rows (128)
    const int brow0 = wave * 16 + (lane >> 2);      // B stage rows (64)
    const int scol  = (lane & 3) * 8;

    f32x4 acc[2][4];
#pragma unroll
    for (int i = 0; i < 2; i++)
#pragma unroll
        for (int j = 0; j < 4; j++)
            acc[i][j] = (f32x4){0.f, 0.f, 0.f, 0.f};

    auto stage = [&](int kt, int buf) {
        const unsigned short* ga0 = A + (size_t)(m0 + arow0) * K + kt + scol;
        const unsigned short* ga1 = A + (size_t)(m0 + arow0 + 16) * K + kt + scol;
        const unsigned short* gb0 = Bt + (size_t)(n0 + brow0) * K + kt + scol;
        unsigned short* as = As + buf * 4096;
        unsigned short* bs = Bs + buf * 2048;
        __builtin_amdgcn_global_load_lds((GUI*)ga0, (LUI*)(as + c0 * 512 + lane * 8), 16, 0, 0);
        __builtin_amdgcn_global_load_lds((GUI*)ga1, (LUI*)(as + (c0 + 1) * 512 + lane * 8), 16, 0, 0);
        __builtin_amdgcn_global_load_lds((GUI*)gb0, (LUI*)(bs + wave * 512 + lane * 8), 16, 0, 0);
    };

    stage(0, 0);
    const int nit = K >> 5;
    for (int it = 0; it < nit; ++it) {
        __syncthreads();
        if (it + 1 < nit) stage((it + 1) << 5, (it + 1) & 1);

        const unsigned short* as = As + (it & 1) * 4096;
        const unsigned short* bs = Bs + (it & 1) * 2048;
        s16x8 a[2], b[4];
#pragma unroll
        for (int mt = 0; mt < 2; mt++)
            a[mt] = *(const s16x8*)(as + (wr + mt * 16 + lc) * 32 + quad * 8);
#pragma unroll
        for (int nb = 0; nb < 4; nb++)
            b[nb] = *(const s16x8*)(bs + (nb * 16 + lc) * 32 + quad * 8);
#pragma unroll
        for (int mt = 0; mt < 2; mt++)
#pragma unroll
            for (int nb = 0; nb < 4; nb++)
                acc[mt][nb] = __builtin_amdgcn_mfma_f32_16x16x32_bf16(a[mt], b[nb], acc[mt][nb], 0, 0, 0);
    }

#pragma unroll
    for (int mt = 0; mt < 2; mt++) {
        const int mb = m0 + wr + mt * 16 + quad * 4;
#pragma unroll
        for (int r = 0; r < 4; r++) {
            float* row = C + (size_t)(mb + r) * N + n0;
#pragma unroll
            for (int nb = 0; nb < 4; nb++)
                row[nb * 16 + lc] = acc[mt][nb][r];
        }
    }
}

// ---------------------------------------------------------------------------
// MFMA causal flash attention v12: v11 (paired-tile 128-key softmax, proven
// -5us) with the cross-lane shuffles removed from the COMMON path:
//  (a) defer-max check runs on PER-LANE partial maxes — `__all(mt_lane<=thr)`
//      is equivalent to the reduced check (m_i is row-uniform; row max <= thr
//      iff all 4 quad-lane partials <= thr). The 2-shfl max reduce moves
//      INSIDE the rarely-taken rescale branch.
//  (b) l is accumulated as a PER-LANE partial (linear in exp terms; alpha is
//      row-uniform so partial*=alpha is consistent); the 2-shfl cross-quad
//      reduce runs ONCE in the epilogue instead of once per pair.
// Common path per 128 keys: per-lane max tree + 1 __all + 32 exp + adds —
// zero cross-lane shuffles (~240 serial cyc/pair removed).
// Staging/barrier schedule byte-identical to v11/v9.
// ---------------------------------------------------------------------------
__global__ __launch_bounds__(256, 3) void attn_mfma12(
    const unsigned short* __restrict__ Qb, const unsigned short* __restrict__ Kb,
    const unsigned short* __restrict__ Vtg, unsigned short* __restrict__ out)
{
    __shared__ __align__(16) unsigned short Ks[2][64 * 64];
    __shared__ __align__(16) unsigned short Vs[2][64 * 64];
    __shared__ __align__(16) unsigned short Ps[8][16 * 72];   // lo: [wave], hi: [wave+4]

    const int tid  = threadIdx.x;
    const int lane = tid & 63;
    const int wave = tid >> 6;           // 0..3
    const int quad = lane >> 4;
    const int lc   = lane & 15;
    const int rsw  = lc & 7;

    const int id   = blockIdx.x;             // 0..1023
    const int bh   = id & 31;                // head-slot; id%8==bh%8 -> XCD-affine
    const int qb   = 31 - (id >> 5);         // longest blocks first
    const int t0   = qb * 64;
    const int n_tiles = qb + 1;

    const size_t headK = (size_t)bh * T_SEQ * HDIM;   // Q,K: (BH,T,64)
    const size_t headV = (size_t)bh * HDIM * T_SEQ;   // Vt:  (BH,64,T)
    const int b = bh >> 4;
    const int h = bh & 15;

    const int c0   = wave * 2;
    const int krow = lane >> 3;
    const int d8sw = (lane & 7) ^ krow;
    unsigned short* pwl = Ps[wave];
    unsigned short* pwh = Ps[wave + 4];

    s16x8 qf0, qf1;
    {
        const size_t qrow = headK + (size_t)(t0 + wave * 16 + lc) * HDIM;
        qf0 = *(const s16x8*)(Qb + qrow + quad * 8);
        qf1 = *(const s16x8*)(Qb + qrow + 32 + quad * 8);
    }

    f32x4 o[4];
    float m_i = -INFINITY;
    float l_p = 0.f;                      // PER-LANE partial row sum
#pragma unroll
    for (int db = 0; db < 4; db++)
        o[db] = (f32x4){0.f, 0.f, 0.f, 0.f};

    auto stage = [&](int s0, int buf) {
        const unsigned short* gk0 = Kb  + headK + (size_t)(s0 + c0 * 8 + krow) * HDIM + d8sw * 8;
        const unsigned short* gk1 = Kb  + headK + (size_t)(s0 + c0 * 8 + 8 + krow) * HDIM + d8sw * 8;
        const unsigned short* gv0 = Vtg + headV + (size_t)(c0 * 8 + krow) * T_SEQ + s0 + d8sw * 8;
        const unsigned short* gv1 = Vtg + headV + (size_t)(c0 * 8 + 8 + krow) * T_SEQ + s0 + d8sw * 8;
        __builtin_amdgcn_global_load_lds((GUI*)gk0, (LUI*)(Ks[buf] + c0 * 512 + lane * 8), 16, 0, 0);
        __builtin_amdgcn_global_load_lds((GUI*)gk1, (LUI*)(Ks[buf] + (c0 + 1) * 512 + lane * 8), 16, 0, 0);
        __builtin_amdgcn_global_load_lds((GUI*)gv0, (LUI*)(Vs[buf] + c0 * 512 + lane * 8), 16, 0, 0);
        __builtin_amdgcn_global_load_lds((GUI*)gv1, (LUI*)(Vs[buf] + (c0 + 1) * 512 + lane * 8), 16, 0, 0);
    };

    auto qk_tile = [&](const unsigned short* ks, f32x4 st[4]) {
        __builtin_amdgcn_s_setprio(1);
#pragma unroll
        for (int kb = 0; kb < 4; kb++) {
            const s16x8 ka0 = *(const s16x8*)&ks[(kb * 16 + lc) * 64 + ((quad ^ rsw) * 8)];
            const s16x8 ka1 = *(const s16x8*)&ks[(kb * 16 + lc) * 64 + (((4 + quad) ^ rsw) * 8)];
            f32x4 z = (f32x4){0.f, 0.f, 0.f, 0.f};
            z = __builtin_amdgcn_mfma_f32_16x16x32_bf16(ka0, qf0, z, 0, 0, 0);
            z = __builtin_amdgcn_mfma_f32_16x16x32_bf16(ka1, qf1, z, 0, 0, 0);
            st[kb] = z;
        }
        __builtin_amdgcn_s_setprio(0);
    };

    auto load_va = [&](const unsigned short* vs, s16x8 va[4][2]) {
#pragma unroll
        for (int db = 0; db < 4; db++) {
            va[db][0] = *(const s16x8*)&vs[(db * 16 + lc) * 64 + ((quad ^ rsw) * 8)];
            va[db][1] = *(const s16x8*)&vs[(db * 16 + lc) * 64 + (((4 + quad) ^ rsw) * 8)];
        }
    };

    auto mask_tile = [&](f32x4 st[4], int s0) {
        const int qrow = t0 + wave * 16 + lc;
#pragma unroll
        for (int kb = 0; kb < 4; kb++) {
            const int key = s0 + kb * 16 + quad * 4;
#pragma unroll
            for (int r = 0; r < 4; r++)
                if (key + r > qrow) st[kb][r] = -INFINITY;
        }
    };

    auto tile_max16 = [&](const f32x4 st[4]) -> float {
        float x0 = fmaxf(fmaxf(st[0][0], st[0][1]), st[0][2]);
        float x1 = fmaxf(fmaxf(st[0][3], st[1][0]), st[1][1]);
        float x2 = fmaxf(fmaxf(st[1][2], st[1][3]), st[2][0]);
        float x3 = fmaxf(fmaxf(st[2][1], st[2][2]), st[2][3]);
        float x4 = fmaxf(fmaxf(st[3][0], st[3][1]), st[3][2]);
        return fmaxf(fmaxf(fmaxf(x0, x1), fmaxf(x2, x3)),
                     fmaxf(x4, st[3][3]));
    };

    // rescale with full cross-lane reduce — only taken when threshold trips
    auto rescale = [&](float mt_lane) {
        float mt = fmaxf(mt_lane, __shfl_xor(mt_lane, 16));
        mt = fmaxf(mt, __shfl_xor(mt, 32));
        const float mn = fmaxf(m_i, mt);
        const float alpha = __builtin_amdgcn_exp2f(m_i - mn);
        m_i = mn;
        l_p *= alpha;
#pragma unroll
        for (int db = 0; db < 4; db++) {
            o[db][0] *= alpha; o[db][1] *= alpha;
            o[db][2] *= alpha; o[db][3] *= alpha;
        }
    };

    const int npairs = n_tiles >> 1;
    stage(0, 0);

    // ---- pair loop: two 64-key sub-tiles, ONE softmax per 128 keys
    for (int p = 0; p < npairs; ++p) {
        const int tlo = 2 * p;
        // sub-tile lo (buf 0)
        __syncthreads();
        if (tlo + 1 < n_tiles) stage((tlo + 1) * 64, 1);
        f32x4 stl[4], sth[4];
        qk_tile(Ks[0], stl);
        s16x8 val[4][2], vah[4][2];
        load_va(Vs[0], val);

        // sub-tile hi (buf 1)
        __syncthreads();
        if (tlo + 2 < n_tiles) stage((tlo + 2) * 64, 0);
        qk_tile(Ks[1], sth);
        load_va(Vs[1], vah);
        if (tlo + 2 == n_tiles) mask_tile(sth, (tlo + 1) * 64);  // hi is diag

        // ---- combined 128-key softmax: per-lane partial max, no shfl on
        //      common path (check equivalence: m_i row-uniform)
        const float mt = fmaxf(tile_max16(stl), tile_max16(sth));
        if (!__all(mt <= m_i + 8.0f)) rescale(mt);   // T13, THR=8 (log2)

        float rs = 0.f;
#pragma unroll
        for (int kb = 0; kb < 4; kb++) {
            const float l0 = __builtin_amdgcn_exp2f(stl[kb][0] - m_i);
            const float h0 = __builtin_amdgcn_exp2f(sth[kb][0] - m_i);
            const float l1 = __builtin_amdgcn_exp2f(stl[kb][1] - m_i);
            const float h1 = __builtin_amdgcn_exp2f(sth[kb][1] - m_i);
            const float l2 = __builtin_amdgcn_exp2f(stl[kb][2] - m_i);
            const float h2 = __builtin_amdgcn_exp2f(sth[kb][2] - m_i);
            const float l3 = __builtin_amdgcn_exp2f(stl[kb][3] - m_i);
            const float h3 = __builtin_amdgcn_exp2f(sth[kb][3] - m_i);
            stl[kb][0] = l0; stl[kb][1] = l1; stl[kb][2] = l2; stl[kb][3] = l3;
            sth[kb][0] = h0; sth[kb][1] = h1; sth[kb][2] = h2; sth[kb][3] = h3;
            rs += ((l0 + l1) + (l2 + l3)) + ((h0 + h1) + (h2 + h3));
        }
        l_p += rs;                        // per-lane partial; reduced at end

        // pack both halves -> P LDS (disjoint per-wave buffers)
#pragma unroll
        for (int kb = 0; kb < 4; kb++) {
            u32x2 pkl, pkh;
            pkl[0] = f2bf_pack2(stl[kb][0], stl[kb][1]);
            pkl[1] = f2bf_pack2(stl[kb][2], stl[kb][3]);
            pkh[0] = f2bf_pack2(sth[kb][0], sth[kb][1]);
            pkh[1] = f2bf_pack2(sth[kb][2], sth[kb][3]);
            *(u32x2*)&pwl[lc * 72 + kb * 16 + quad * 4] = pkl;
            *(u32x2*)&pwh[lc * 72 + kb * 16 + quad * 4] = pkh;
        }
        const s16x8 pb0l = *(const s16x8*)&pwl[lc * 72 + quad * 8];
        const s16x8 pb1l = *(const s16x8*)&pwl[lc * 72 + 32 + quad * 8];
        const s16x8 pb0h = *(const s16x8*)&pwh[lc * 72 + quad * 8];
        const s16x8 pb1h = *(const s16x8*)&pwh[lc * 72 + 32 + quad * 8];
        __builtin_amdgcn_s_setprio(1);
#pragma unroll
        for (int db = 0; db < 4; db++) {
            o[db] = __builtin_amdgcn_mfma_f32_16x16x32_bf16(val[db][0], pb0l, o[db], 0, 0, 0);
            o[db] = __builtin_amdgcn_mfma_f32_16x16x32_bf16(val[db][1], pb1l, o[db], 0, 0, 0);
            o[db] = __builtin_amdgcn_mfma_f32_16x16x32_bf16(vah[db][0], pb0h, o[db], 0, 0, 0);
            o[db] = __builtin_amdgcn_mfma_f32_16x16x32_bf16(vah[db][1], pb1h, o[db], 0, 0, 0);
        }
        __builtin_amdgcn_s_setprio(0);
    }

    // ---- odd tail: single 64-key tile (always the diagonal, buf 0)
    if (n_tiles & 1) {
        __syncthreads();
        f32x4 st[4];
        qk_tile(Ks[0], st);
        s16x8 va[4][2];
        load_va(Vs[0], va);
        mask_tile(st, (n_tiles - 1) * 64);

        const float mt = tile_max16(st);
        if (!__all(mt <= m_i + 8.0f)) rescale(mt);

        float rs = 0.f;
#pragma unroll
        for (int kb = 0; kb < 4; kb++) {
            const float e0 = __builtin_amdgcn_exp2f(st[kb][0] - m_i);
            const float e1 = __builtin_amdgcn_exp2f(st[kb][1] - m_i);
            const float e2 = __builtin_amdgcn_exp2f(st[kb][2] - m_i);
            const float e3 = __builtin_amdgcn_exp2f(st[kb][3] - m_i);
            st[kb][0] = e0; st[kb][1] = e1; st[kb][2] = e2; st[kb][3] = e3;
            rs += (e0 + e1) + (e2 + e3);
        }
        l_p += rs;

#pragma unroll
        for (int kb = 0; kb < 4; kb++) {
            u32x2 pk;
            pk[0] = f2bf_pack2(st[kb][0], st[kb][1]);
            pk[1] = f2bf_pack2(st[kb][2], st[kb][3]);
            *(u32x2*)&pwl[lc * 72 + kb * 16 + quad * 4] = pk;
        }
        const s16x8 pb0 = *(const s16x8*)&pwl[lc * 72 + quad * 8];
        const s16x8 pb1 = *(const s16x8*)&pwl[lc * 72 + 32 + quad * 8];
        __builtin_amdgcn_s_setprio(1);
#pragma unroll
        for (int db = 0; db < 4; db++) {
            o[db] = __builtin_amdgcn_mfma_f32_16x16x32_bf16(va[db][0], pb0, o[db], 0, 0, 0);
            o[db] = __builtin_amdgcn_mfma_f32_16x16x32_bf16(va[db][1], pb1, o[db], 0, 0, 0);
        }
        __builtin_amdgcn_s_setprio(0);
    }

    // ---- epilogue: ONE cross-quad l reduction for the whole block
    {
        float l_i = l_p;
        l_i += __shfl_xor(l_i, 16);
        l_i += __shfl_xor(l_i, 32);
        const float inv_l = 1.f / l_i;
        const int t = t0 + wave * 16 + lc;
        unsigned short* orow = out + (size_t)(b * T_SEQ + t) * DMODEL + h * HDIM + quad * 4;
#pragma unroll
        for (int db = 0; db < 4; db++) {
            u32x2 pk;
            pk[0] = f2bf_pack2(o[db][0] * inv_l, o[db][1] * inv_l);
            pk[1] = f2bf_pack2(o[db][2] * inv_l, o[db][3] * inv_l);
            *(u32x2*)(orow + db * 16) = pk;
        }
    }
}

// ---------------------------------------------------------------------------
extern "C" void kernel_launch(void* const* d_in, const int* in_sizes, int n_in,
                              void* d_out, int out_size, void* d_ws, size_t ws_size,
                              hipStream_t stream)
{
    const float* x    = (const float*)d_in[0];   // (B,T,D) fp32
    const float* Wqkv = (const float*)d_in[1];   // (D,3D) fp32
    const float* Wout = (const float*)d_in[2];   // (D,D) fp32
    // d_in[3] attn_mask: causal triu(k=1), applied analytically.

    float* out = (float*)d_out;

    char* ws = (char*)d_ws;
    unsigned short* attnb  = (unsigned short*)(ws);               // (B,T,D) bf16, 8 MB
    unsigned short* Qb     = (unsigned short*)(ws + (8u  << 20)); // (B,H,T,64)
    unsigned short* Kb     = (unsigned short*)(ws + (16u << 20)); // (B,H,T,64)
    unsigned short* Vt     = (unsigned short*)(ws + (24u << 20)); // (B,H,64,T)
    unsigned short* xbuf   = (unsigned short*)(ws + (32u << 20)); // (M,K) bf16
    unsigned short* Wqkv_t = (unsigned short*)(ws + (40u << 20)); // (3D,D) bf16
    unsigned short* Wout_t = (unsigned short*)(ws + (46u << 20)); // (D,D) bf16
    float2*         ropeT  = (float2*)       (ws + (48u << 20)); // 2048x32 float2, 512 KB

    // 0) fused prep: convert x, transpose weights, build RoPE table
    prep_fused<<<dim3(3328), 256, 0, stream>>>(x, Wqkv, Wout, xbuf, Wqkv_t, Wout_t, ropeT);

    // 1) QKV MFMA GEMM (dbuf, XCD-affine) + RoPE table + scale + pack
    gemm_qkv_rope_mfma<<<dim3(768), 256, 0, stream>>>(xbuf, Wqkv_t, ropeT, Qb, Kb, Vt);

    // 2) MFMA causal flash attention v12 (paired softmax, shuffle-free path)
    attn_mfma12<<<dim3(1024), 256, 0, stream>>>(Qb, Kb, Vt, attnb);

    // 3) out = attnb @ Wout  (fp32 out, 128x64 tile, 2 blocks/CU)
    gemm_out_mfma<<<dim3(512), 256, 0, stream>>>(attnb, Wout_t, out, DMODEL, DMODEL);
}

// Round 11
// 186.444 us; speedup vs baseline: 1.0812x; 1.0069x over previous
//
#include <hip/hip_runtime.h>
#include <math.h>

#define BATCH   2
#define T_SEQ   2048
#define DMODEL  1024
#define NHEAD   16
#define HDIM    64

typedef short s16x8 __attribute__((ext_vector_type(8)));
typedef unsigned short u16x8 __attribute__((ext_vector_type(8)));
typedef unsigned short u16x4 __attribute__((ext_vector_type(4)));
typedef unsigned int u32x2 __attribute__((ext_vector_type(2)));
typedef float f32x4 __attribute__((ext_vector_type(4)));

typedef const unsigned int __attribute__((address_space(1))) GUI;
typedef unsigned int __attribute__((address_space(3))) LUI;

// fp32 -> bf16 round-to-nearest-even (bit pattern)
static __device__ __forceinline__ unsigned short f2bf(float f) {
    unsigned int u = __float_as_uint(f);
    u += 0x7fffu + ((u >> 16) & 1u);
    return (unsigned short)(u >> 16);
}

// two fp32 -> packed bf16x2 (round-half-up) via one v_perm_b32
static __device__ __forceinline__ unsigned int f2bf_pack2(float a, float b) {
    const unsigned int ua = __float_as_uint(a) + 0x8000u;
    const unsigned int ub = __float_as_uint(b) + 0x8000u;
    return __builtin_amdgcn_perm(ub, ua, 0x07060302u);
}

// ---------------------------------------------------------------------------
// Fused prep: blocks 0..2047 convert x -> bf16; 2048..2815 transpose Wqkv;
// 2816..3071 transpose Wout; 3072..3327 build RoPE cos/sin table.
// v2 transpose (G13): float4 ingest + u16x4 LDS writes, u16x4 (8B) egress
// stores — 64 -> 28 mem instructions/thread, 4x wider loads and stores.
// Output layouts unchanged (consumers untouched).
// ---------------------------------------------------------------------------
__global__ __launch_bounds__(256) void prep_fused(
    const float* __restrict__ x, const float* __restrict__ Wqkv,
    const float* __restrict__ Wout,
    unsigned short* __restrict__ xb, unsigned short* __restrict__ Wqkv_t,
    unsigned short* __restrict__ Wout_t, float2* __restrict__ rope_tab)
{
    __shared__ unsigned short tile[64][68];
    const int bid = blockIdx.x;
    const int tid = threadIdx.x;

    if (bid < 2048) {
        const int i = bid * 256 + tid;
        const float4 a = ((const float4*)x)[2 * i];
        const float4 b = ((const float4*)x)[2 * i + 1];
        u16x8 r;
        r[0] = f2bf(a.x); r[1] = f2bf(a.y); r[2] = f2bf(a.z); r[3] = f2bf(a.w);
        r[4] = f2bf(b.x); r[5] = f2bf(b.y); r[6] = f2bf(b.z); r[7] = f2bf(b.w);
        ((u16x8*)xb)[i] = r;
        return;
    }
    if (bid >= 3072) {
        const int idx = (bid - 3072) * 256 + tid;
        const int t = idx >> 5;
        const int d2 = idx & 31;
        const float inv_freq = exp2f(-(float)d2 * 0.41524101186092029f); // log2(1e4)/32
        float s, c;
        sincosf((float)t * inv_freq, &s, &c);
        rope_tab[idx] = make_float2(c, s);
        return;
    }

    const float* src;
    unsigned short* dst;
    int R, C, bx, by;
    if (bid < 2816) {
        const int id = bid - 2048;
        src = Wqkv; dst = Wqkv_t; R = DMODEL; C = 3 * DMODEL;
        bx = id % 48; by = id / 48;
    } else {
        const int id = bid - 2816;
        src = Wout; dst = Wout_t; R = DMODEL; C = DMODEL;
        bx = id % 16; by = id / 16;
    }
    const int tc0 = bx * 64;
    const int tr0 = by * 64;

    // phase 1: float4 loads (16 lanes span 64 cols; 4 row-chunks of 16)
    {
        const int cg = tid & 15;          // float4-column group
        const int r0 = tid >> 4;          // 0..15
#pragma unroll
        for (int k = 0; k < 4; k++) {
            const int row = r0 + 16 * k;
            const float4 v = *(const float4*)&src[(size_t)(tr0 + row) * C + tc0 + cg * 4];
            u16x4 pk;
            pk[0] = f2bf(v.x); pk[1] = f2bf(v.y);
            pk[2] = f2bf(v.z); pk[3] = f2bf(v.w);
            *(u16x4*)&tile[row][cg * 4] = pk;
        }
    }
    __syncthreads();
    // phase 2: transposed egress, u16x4 (8B) stores (16 lanes = 128B runs)
    {
        const int rq = tid & 15;          // row-quad: rows rq*4..rq*4+3
        const int c0 = tid >> 4;          // 0..15
#pragma unroll
        for (int k = 0; k < 4; k++) {
            const int c = c0 + 16 * k;
            u16x4 pk;
            pk[0] = tile[rq * 4 + 0][c];
            pk[1] = tile[rq * 4 + 1][c];
            pk[2] = tile[rq * 4 + 2][c];
            pk[3] = tile[rq * 4 + 3][c];
            *(u16x4*)&dst[(size_t)(tc0 + c) * R + tr0 + rq * 4] = pk;
        }
    }
}

// ---------------------------------------------------------------------------
// Shared MFMA GEMM main loop, DOUBLE-BUFFERED, one barrier per K-slice.
// (Round-0 proven form — do not touch; see session notes: 8-phase x2 and
// counted-vmcnt 3-buf all lost their A/B. LDS-swizzle (T2) intentionally NOT
// applied: catalog m230/m252 shows T2 is null on 2-barrier structures —
// the stage+vmcnt+barrier critical path hides LDS-read conflicts.)
// ---------------------------------------------------------------------------
__device__ __forceinline__ void mfma_gemm_loop_db(
    const unsigned short* __restrict__ A, const unsigned short* __restrict__ Bt,
    unsigned short* As, unsigned short* Bs,
    int m0, int n0, int K, f32x4 acc[4][4])
{
    const int tid  = threadIdx.x;
    const int wave = tid >> 6;
    const int lane = tid & 63;
    const int quad = lane >> 4;
    const int lc   = lane & 15;
    const int wr   = (wave >> 1) * 64;
    const int wc   = (wave & 1) * 64;

    const int c0    = wave * 2;
    const int srow0 = c0 * 16 + (lane >> 2);
    const int scol  = (lane & 3) * 8;

#pragma unroll
    for (int i = 0; i < 4; i++)
#pragma unroll
        for (int j = 0; j < 4; j++)
            acc[i][j] = (f32x4){0.f, 0.f, 0.f, 0.f};

    auto stage = [&](int kt, int buf) {
        const unsigned short* ga0 = A + (size_t)(m0 + srow0) * K + kt + scol;
        const unsigned short* ga1 = A + (size_t)(m0 + srow0 + 16) * K + kt + scol;
        const unsigned short* gb0 = Bt + (size_t)(n0 + srow0) * K + kt + scol;
        const unsigned short* gb1 = Bt + (size_t)(n0 + srow0 + 16) * K + kt + scol;
        unsigned short* as = As + buf * 4096;
        unsigned short* bs = Bs + buf * 4096;
        __builtin_amdgcn_global_load_lds((GUI*)ga0, (LUI*)(as + c0 * 512 + lane * 8), 16, 0, 0);
        __builtin_amdgcn_global_load_lds((GUI*)ga1, (LUI*)(as + (c0 + 1) * 512 + lane * 8), 16, 0, 0);
        __builtin_amdgcn_global_load_lds((GUI*)gb0, (LUI*)(bs + c0 * 512 + lane * 8), 16, 0, 0);
        __builtin_amdgcn_global_load_lds((GUI*)gb1, (LUI*)(bs + (c0 + 1) * 512 + lane * 8), 16, 0, 0);
    };

    stage(0, 0);
    const int nit = K >> 5;
    for (int it = 0; it < nit; ++it) {
        __syncthreads();
        if (it + 1 < nit) stage((it + 1) << 5, (it + 1) & 1);

        const unsigned short* as = As + (it & 1) * 4096;
        const unsigned short* bs = Bs + (it & 1) * 4096;
        s16x8 a[4], b[4];
#pragma unroll
        for (int mt = 0; mt < 4; mt++)
            a[mt] = *(const s16x8*)(as + (wr + mt * 16 + lc) * 32 + quad * 8);
#pragma unroll
        for (int nb = 0; nb < 4; nb++)
            b[nb] = *(const s16x8*)(bs + (wc + nb * 16 + lc) * 32 + quad * 8);
#pragma unroll
        for (int mt = 0; mt < 4; mt++)
#pragma unroll
            for (int nb = 0; nb < 4; nb++)
                acc[mt][nb] = __builtin_amdgcn_mfma_f32_16x16x32_bf16(a[mt], b[nb], acc[mt][nb], 0, 0, 0);
    }
}

// ---------------------------------------------------------------------------
// QKV GEMM (bf16 MFMA, dbuf) + RoPE (table lookup) + Q-scale + pack.
// 1-D grid 768, XCD-affine. (Round-0 proven version: ~48 us.)
// ---------------------------------------------------------------------------
__global__ __launch_bounds__(256) void gemm_qkv_rope_mfma(
    const unsigned short* __restrict__ xb, const unsigned short* __restrict__ Wt,
    const float2* __restrict__ rope_tab,
    unsigned short* __restrict__ Qb, unsigned short* __restrict__ Kb,
    unsigned short* __restrict__ Vb)
{
    __shared__ __align__(16) unsigned short As[2 * 128 * 32];
    __shared__ __align__(16) unsigned short Bs[2 * 128 * 32];

    const int id  = blockIdx.x;               // 0..767
    const int s   = id >> 3;                  // 0..95
    const int n0  = ((id & 7) * 3 + (s % 3)) * 128;
    const int m0  = (s / 3) * 128;
    f32x4 acc[4][4];
    mfma_gemm_loop_db(xb, Wt, As, Bs, m0, n0, DMODEL, acc);

    const int lane = threadIdx.x & 63;
    const int wave = threadIdx.x >> 6;
    const int quad = lane >> 4;
    const int lc   = lane & 15;
    const int wr   = (wave >> 1) * 64;
    const int wc   = (wave & 1) * 64;

    const int n_base = n0 + wc;
    const int part = n_base >> 10;       // 0=q 1=k 2=v, uniform per block
    unsigned short* dst = (part == 0) ? Qb : (part == 1 ? Kb : Vb);
    const float scale = (part == 0) ? 0.125f * 1.4426950408889634f : 1.0f;

#pragma unroll
    for (int nb = 0; nb < 4; nb++) {
        const int n = n_base + nb * 16 + lc;
        const int h = (n >> 6) & 15;
        const int d = n & 63;
        if (part == 2) {
#pragma unroll
            for (int mt = 0; mt < 4; mt++) {
                const int mb = m0 + wr + mt * 16 + quad * 4;
                const int bb = mb >> 11, t = mb & 2047;
                u16x4 pk;
                pk[0] = f2bf(acc[mt][nb][0]); pk[1] = f2bf(acc[mt][nb][1]);
                pk[2] = f2bf(acc[mt][nb][2]); pk[3] = f2bf(acc[mt][nb][3]);
                *(u16x4*)&dst[((size_t)(bb * NHEAD + h) * HDIM + d) * T_SEQ + t] = pk;
            }
        } else {
            const size_t hb = (size_t)h * T_SEQ * HDIM + d;
            const int d2 = d >> 1;
            const float ssign = (lc & 1) ? 1.f : -1.f;
#pragma unroll
            for (int mt = 0; mt < 4; mt++) {
                const int mb = m0 + wr + mt * 16 + quad * 4;
#pragma unroll
                for (int r = 0; r < 4; r++) {
                    const float val = acc[mt][nb][r];
                    const float prt = __shfl_xor(val, 1);
                    const int m = mb + r;
                    const int bb = m >> 11, t = m & 2047;
                    const float2 sc = rope_tab[t * 32 + d2];   // (cos, sin)
                    const float res = fmaf(prt, ssign * sc.y, val * sc.x) * scale;
                    dst[(size_t)bb * NHEAD * T_SEQ * HDIM + hb + (size_t)t * HDIM] = f2bf(res);
                }
            }
        }
    }
}

// ---------------------------------------------------------------------------
// Out-proj GEMM v2: 128x64 tile, grid 512 = 2 blocks/CU.
// ---------------------------------------------------------------------------
__global__ __launch_bounds__(256) void gemm_out_mfma(
    const unsigned short* __restrict__ A, const unsigned short* __restrict__ Bt,
    float* __restrict__ C, int N, int K)
{
    __shared__ __align__(16) unsigned short As[2 * 128 * 32];  // 16 KB
    __shared__ __align__(16) unsigned short Bs[2 * 64 * 32];   //  8 KB

    const int id = blockIdx.x;            // 0..511
    const int s  = id >> 3;               // 0..63
    const int n0 = ((id & 7) * 2 + (s & 1)) * 64;   // 16 n-blocks, XCD-affine
    const int m0 = (s >> 1) * 128;                  // 32 m-blocks

    const int tid  = threadIdx.x;
    const int wave = tid >> 6;
    const int lane = tid & 63;
    const int quad = lane >> 4;
    const int lc   = lane & 15;
    const int wr   = wave * 32;           // 4 waves stacked along M

    const int c0    = wave * 2;
    const int arow0 = c0 * 16 + (lane >> 2);        // A stage rows (128)
    const int brow0 = wave * 16 + (lane >> 2);      // B stage rows (64)
    const int scol  = (lane & 3) * 8;

    f32x4 acc[2][4];
#pragma unroll
    for (int i = 0; i < 2; i++)
#pragma unroll
        for (int j = 0; j < 4; j++)
            acc[i][j] = (f32x4){0.f, 0.f, 0.f, 0.f};

    auto stage = [&](int kt, int buf) {
        const unsigned short* ga0 = A + (size_t)(m0 + arow0) * K + kt + scol;
        const unsigned short* ga1 = A + (size_t)(m0 + arow0 + 16) * K + kt + scol;
        const unsigned short* gb0 = Bt + (size_t)(n0 + brow0) * K + kt + scol;
        unsigned short* as = As + buf * 4096;
        unsigned short* bs = Bs + buf * 2048;
        __builtin_amdgcn_global_load_lds((GUI*)ga0, (LUI*)(as + c0 * 512 + lane * 8), 16, 0, 0);
        __builtin_amdgcn_global_load_lds((GUI*)ga1, (LUI*)(as + (c0 + 1) * 512 + lane * 8), 16, 0, 0);
        __builtin_amdgcn_global_load_lds((GUI*)gb0, (LUI*)(bs + wave * 512 + lane * 8), 16, 0, 0);
    };

    stage(0, 0);
    const int nit = K >> 5;
    for (int it = 0; it < nit; ++it) {
        __syncthreads();
        if (it + 1 < nit) stage((it + 1) << 5, (it + 1) & 1);

        const unsigned short* as = As + (it & 1) * 4096;
        const unsigned short* bs = Bs + (it & 1) * 2048;
        s16x8 a[2], b[4];
#pragma unroll
        for (int mt = 0; mt < 2; mt++)
            a[mt] = *(const s16x8*)(as + (wr + mt * 16 + lc) * 32 + quad * 8);
#pragma unroll
        for (int nb = 0; nb < 4; nb++)
            b[nb] = *(const s16x8*)(bs + (nb * 16 + lc) * 32 + quad * 8);
#pragma unroll
        for (int mt = 0; mt < 2; mt++)
#pragma unroll
            for (int nb = 0; nb < 4; nb++)
                acc[mt][nb] = __builtin_amdgcn_mfma_f32_16x16x32_bf16(a[mt], b[nb], acc[mt][nb], 0, 0, 0);
    }

#pragma unroll
    for (int mt = 0; mt < 2; mt++) {
        const int mb = m0 + wr + mt * 16 + quad * 4;
#pragma unroll
        for (int r = 0; r < 4; r++) {
            float* row = C + (size_t)(mb + r) * N + n0;
#pragma unroll
            for (int nb = 0; nb < 4; nb++)
                row[nb * 16 + lc] = acc[mt][nb][r];
        }
    }
}

// ---------------------------------------------------------------------------
// MFMA causal flash attention v12: paired-tile 128-key softmax with
// shuffle-free common path (session wins: v11 -5us, v12 -3us).
// ---------------------------------------------------------------------------
__global__ __launch_bounds__(256, 3) void attn_mfma12(
    const unsigned short* __restrict__ Qb, const unsigned short* __restrict__ Kb,
    const unsigned short* __restrict__ Vtg, unsigned short* __restrict__ out)
{
    __shared__ __align__(16) unsigned short Ks[2][64 * 64];
    __shared__ __align__(16) unsigned short Vs[2][64 * 64];
    __shared__ __align__(16) unsigned short Ps[8][16 * 72];   // lo: [wave], hi: [wave+4]

    const int tid  = threadIdx.x;
    const int lane = tid & 63;
    const int wave = tid >> 6;           // 0..3
    const int quad = lane >> 4;
    const int lc   = lane & 15;
    const int rsw  = lc & 7;

    const int id   = blockIdx.x;             // 0..1023
    const int bh   = id & 31;                // head-slot; id%8==bh%8 -> XCD-affine
    const int qb   = 31 - (id >> 5);         // longest blocks first
    const int t0   = qb * 64;
    const int n_tiles = qb + 1;

    const size_t headK = (size_t)bh * T_SEQ * HDIM;   // Q,K: (BH,T,64)
    const size_t headV = (size_t)bh * HDIM * T_SEQ;   // Vt:  (BH,64,T)
    const int b = bh >> 4;
    const int h = bh & 15;

    const int c0   = wave * 2;
    const int krow = lane >> 3;
    const int d8sw = (lane & 7) ^ krow;
    unsigned short* pwl = Ps[wave];
    unsigned short* pwh = Ps[wave + 4];

    s16x8 qf0, qf1;
    {
        const size_t qrow = headK + (size_t)(t0 + wave * 16 + lc) * HDIM;
        qf0 = *(const s16x8*)(Qb + qrow + quad * 8);
        qf1 = *(const s16x8*)(Qb + qrow + 32 + quad * 8);
    }

    f32x4 o[4];
    float m_i = -INFINITY;
    float l_p = 0.f;                      // PER-LANE partial row sum
#pragma unroll
    for (int db = 0; db < 4; db++)
        o[db] = (f32x4){0.f, 0.f, 0.f, 0.f};

    auto stage = [&](int s0, int buf) {
        const unsigned short* gk0 = Kb  + headK + (size_t)(s0 + c0 * 8 + krow) * HDIM + d8sw * 8;
        const unsigned short* gk1 = Kb  + headK + (size_t)(s0 + c0 * 8 + 8 + krow) * HDIM + d8sw * 8;
        const unsigned short* gv0 = Vtg + headV + (size_t)(c0 * 8 + krow) * T_SEQ + s0 + d8sw * 8;
        const unsigned short* gv1 = Vtg + headV + (size_t)(c0 * 8 + 8 + krow) * T_SEQ + s0 + d8sw * 8;
        __builtin_amdgcn_global_load_lds((GUI*)gk0, (LUI*)(Ks[buf] + c0 * 512 + lane * 8), 16, 0, 0);
        __builtin_amdgcn_global_load_lds((GUI*)gk1, (LUI*)(Ks[buf] + (c0 + 1) * 512 + lane * 8), 16, 0, 0);
        __builtin_amdgcn_global_load_lds((GUI*)gv0, (LUI*)(Vs[buf] + c0 * 512 + lane * 8), 16, 0, 0);
        __builtin_amdgcn_global_load_lds((GUI*)gv1, (LUI*)(Vs[buf] + (c0 + 1) * 512 + lane * 8), 16, 0, 0);
    };

    auto qk_tile = [&](const unsigned short* ks, f32x4 st[4]) {
        __builtin_amdgcn_s_setprio(1);
#pragma unroll
        for (int kb = 0; kb < 4; kb++) {
            const s16x8 ka0 = *(const s16x8*)&ks[(kb * 16 + lc) * 64 + ((quad ^ rsw) * 8)];
            const s16x8 ka1 = *(const s16x8*)&ks[(kb * 16 + lc) * 64 + (((4 + quad) ^ rsw) * 8)];
            f32x4 z = (f32x4){0.f, 0.f, 0.f, 0.f};
            z = __builtin_amdgcn_mfma_f32_16x16x32_bf16(ka0, qf0, z, 0, 0, 0);
            z = __builtin_amdgcn_mfma_f32_16x16x32_bf16(ka1, qf1, z, 0, 0, 0);
            st[kb] = z;
        }
        __builtin_amdgcn_s_setprio(0);
    };

    auto load_va = [&](const unsigned short* vs, s16x8 va[4][2]) {
#pragma unroll
        for (int db = 0; db < 4; db++) {
            va[db][0] = *(const s16x8*)&vs[(db * 16 + lc) * 64 + ((quad ^ rsw) * 8)];
            va[db][1] = *(const s16x8*)&vs[(db * 16 + lc) * 64 + (((4 + quad) ^ rsw) * 8)];
        }
    };

    auto mask_tile = [&](f32x4 st[4], int s0) {
        const int qrow = t0 + wave * 16 + lc;
#pragma unroll
        for (int kb = 0; kb < 4; kb++) {
            const int key = s0 + kb * 16 + quad * 4;
#pragma unroll
            for (int r = 0; r < 4; r++)
                if (key + r > qrow) st[kb][r] = -INFINITY;
        }
    };

    auto tile_max16 = [&](const f32x4 st[4]) -> float {
        float x0 = fmaxf(fmaxf(st[0][0], st[0][1]), st[0][2]);
        float x1 = fmaxf(fmaxf(st[0][3], st[1][0]), st[1][1]);
        float x2 = fmaxf(fmaxf(st[1][2], st[1][3]), st[2][0]);
        float x3 = fmaxf(fmaxf(st[2][1], st[2][2]), st[2][3]);
        float x4 = fmaxf(fmaxf(st[3][0], st[3][1]), st[3][2]);
        return fmaxf(fmaxf(fmaxf(x0, x1), fmaxf(x2, x3)),
                     fmaxf(x4, st[3][3]));
    };

    // rescale with full cross-lane reduce — only taken when threshold trips
    auto rescale = [&](float mt_lane) {
        float mt = fmaxf(mt_lane, __shfl_xor(mt_lane, 16));
        mt = fmaxf(mt, __shfl_xor(mt, 32));
        const float mn = fmaxf(m_i, mt);
        const float alpha = __builtin_amdgcn_exp2f(m_i - mn);
        m_i = mn;
        l_p *= alpha;
#pragma unroll
        for (int db = 0; db < 4; db++) {
            o[db][0] *= alpha; o[db][1] *= alpha;
            o[db][2] *= alpha; o[db][3] *= alpha;
        }
    };

    const int npairs = n_tiles >> 1;
    stage(0, 0);

    // ---- pair loop: two 64-key sub-tiles, ONE softmax per 128 keys
    for (int p = 0; p < npairs; ++p) {
        const int tlo = 2 * p;
        // sub-tile lo (buf 0)
        __syncthreads();
        if (tlo + 1 < n_tiles) stage((tlo + 1) * 64, 1);
        f32x4 stl[4], sth[4];
        qk_tile(Ks[0], stl);
        s16x8 val[4][2], vah[4][2];
        load_va(Vs[0], val);

        // sub-tile hi (buf 1)
        __syncthreads();
        if (tlo + 2 < n_tiles) stage((tlo + 2) * 64, 0);
        qk_tile(Ks[1], sth);
        load_va(Vs[1], vah);
        if (tlo + 2 == n_tiles) mask_tile(sth, (tlo + 1) * 64);  // hi is diag

        // ---- combined 128-key softmax: per-lane partial max, no shfl on
        //      common path (check equivalence: m_i row-uniform)
        const float mt = fmaxf(tile_max16(stl), tile_max16(sth));
        if (!__all(mt <= m_i + 8.0f)) rescale(mt);   // T13, THR=8 (log2)

        float rs = 0.f;
#pragma unroll
        for (int kb = 0; kb < 4; kb++) {
            const float l0 = __builtin_amdgcn_exp2f(stl[kb][0] - m_i);
            const float h0 = __builtin_amdgcn_exp2f(sth[kb][0] - m_i);
            const float l1 = __builtin_amdgcn_exp2f(stl[kb][1] - m_i);
            const float h1 = __builtin_amdgcn_exp2f(sth[kb][1] - m_i);
            const float l2 = __builtin_amdgcn_exp2f(stl[kb][2] - m_i);
            const float h2 = __builtin_amdgcn_exp2f(sth[kb][2] - m_i);
            const float l3 = __builtin_amdgcn_exp2f(stl[kb][3] - m_i);
            const float h3 = __builtin_amdgcn_exp2f(sth[kb][3] - m_i);
            stl[kb][0] = l0; stl[kb][1] = l1; stl[kb][2] = l2; stl[kb][3] = l3;
            sth[kb][0] = h0; sth[kb][1] = h1; sth[kb][2] = h2; sth[kb][3] = h3;
            rs += ((l0 + l1) + (l2 + l3)) + ((h0 + h1) + (h2 + h3));
        }
        l_p += rs;                        // per-lane partial; reduced at end

        // pack both halves -> P LDS (disjoint per-wave buffers)
#pragma unroll
        for (int kb = 0; kb < 4; kb++) {
            u32x2 pkl, pkh;
            pkl[0] = f2bf_pack2(stl[kb][0], stl[kb][1]);
            pkl[1] = f2bf_pack2(stl[kb][2], stl[kb][3]);
            pkh[0] = f2bf_pack2(sth[kb][0], sth[kb][1]);
            pkh[1] = f2bf_pack2(sth[kb][2], sth[kb][3]);
            *(u32x2*)&pwl[lc * 72 + kb * 16 + quad * 4] = pkl;
            *(u32x2*)&pwh[lc * 72 + kb * 16 + quad * 4] = pkh;
        }
        const s16x8 pb0l = *(const s16x8*)&pwl[lc * 72 + quad * 8];
        const s16x8 pb1l = *(const s16x8*)&pwl[lc * 72 + 32 + quad * 8];
        const s16x8 pb0h = *(const s16x8*)&pwh[lc * 72 + quad * 8];
        const s16x8 pb1h = *(const s16x8*)&pwh[lc * 72 + 32 + quad * 8];
        __builtin_amdgcn_s_setprio(1);
#pragma unroll
        for (int db = 0; db < 4; db++) {
            o[db] = __builtin_amdgcn_mfma_f32_16x16x32_bf16(val[db][0], pb0l, o[db], 0, 0, 0);
            o[db] = __builtin_amdgcn_mfma_f32_16x16x32_bf16(val[db][1], pb1l, o[db], 0, 0, 0);
            o[db] = __builtin_amdgcn_mfma_f32_16x16x32_bf16(vah[db][0], pb0h, o[db], 0, 0, 0);
            o[db] = __builtin_amdgcn_mfma_f32_16x16x32_bf16(vah[db][1], pb1h, o[db], 0, 0, 0);
        }
        __builtin_amdgcn_s_setprio(0);
    }

    // ---- odd tail: single 64-key tile (always the diagonal, buf 0)
    if (n_tiles & 1) {
        __syncthreads();
        f32x4 st[4];
        qk_tile(Ks[0], st);
        s16x8 va[4][2];
        load_va(Vs[0], va);
        mask_tile(st, (n_tiles - 1) * 64);

        const float mt = tile_max16(st);
        if (!__all(mt <= m_i + 8.0f)) rescale(mt);

        float rs = 0.f;
#pragma unroll
        for (int kb = 0; kb < 4; kb++) {
            const float e0 = __builtin_amdgcn_exp2f(st[kb][0] - m_i);
            const float e1 = __builtin_amdgcn_exp2f(st[kb][1] - m_i);
            const float e2 = __builtin_amdgcn_exp2f(st[kb][2] - m_i);
            const float e3 = __builtin_amdgcn_exp2f(st[kb][3] - m_i);
            st[kb][0] = e0; st[kb][1] = e1; st[kb][2] = e2; st[kb][3] = e3;
            rs += (e0 + e1) + (e2 + e3);
        }
        l_p += rs;

#pragma unroll
        for (int kb = 0; kb < 4; kb++) {
            u32x2 pk;
            pk[0] = f2bf_pack2(st[kb][0], st[kb][1]);
            pk[1] = f2bf_pack2(st[kb][2], st[kb][3]);
            *(u32x2*)&pwl[lc * 72 + kb * 16 + quad * 4] = pk;
        }
        const s16x8 pb0 = *(const s16x8*)&pwl[lc * 72 + quad * 8];
        const s16x8 pb1 = *(const s16x8*)&pwl[lc * 72 + 32 + quad * 8];
        __builtin_amdgcn_s_setprio(1);
#pragma unroll
        for (int db = 0; db < 4; db++) {
            o[db] = __builtin_amdgcn_mfma_f32_16x16x32_bf16(va[db][0], pb0, o[db], 0, 0, 0);
            o[db] = __builtin_amdgcn_mfma_f32_16x16x32_bf16(va[db][1], pb1, o[db], 0, 0, 0);
        }
        __builtin_amdgcn_s_setprio(0);
    }

    // ---- epilogue: ONE cross-quad l reduction for the whole block
    {
        float l_i = l_p;
        l_i += __shfl_xor(l_i, 16);
        l_i += __shfl_xor(l_i, 32);
        const float inv_l = 1.f / l_i;
        const int t = t0 + wave * 16 + lc;
        unsigned short* orow = out + (size_t)(b * T_SEQ + t) * DMODEL + h * HDIM + quad * 4;
#pragma unroll
        for (int db = 0; db < 4; db++) {
            u32x2 pk;
            pk[0] = f2bf_pack2(o[db][0] * inv_l, o[db][1] * inv_l);
            pk[1] = f2bf_pack2(o[db][2] * inv_l, o[db][3] * inv_l);
            *(u32x2*)(orow + db * 16) = pk;
        }
    }
}

// ---------------------------------------------------------------------------
extern "C" void kernel_launch(void* const* d_in, const int* in_sizes, int n_in,
                              void* d_out, int out_size, void* d_ws, size_t ws_size,
                              hipStream_t stream)
{
    const float* x    = (const float*)d_in[0];   // (B,T,D) fp32
    const float* Wqkv = (const float*)d_in[1];   // (D,3D) fp32
    const float* Wout = (const float*)d_in[2];   // (D,D) fp32
    // d_in[3] attn_mask: causal triu(k=1), applied analytically.

    float* out = (float*)d_out;

    char* ws = (char*)d_ws;
    unsigned short* attnb  = (unsigned short*)(ws);               // (B,T,D) bf16, 8 MB
    unsigned short* Qb     = (unsigned short*)(ws + (8u  << 20)); // (B,H,T,64)
    unsigned short* Kb     = (unsigned short*)(ws + (16u << 20)); // (B,H,T,64)
    unsigned short* Vt     = (unsigned short*)(ws + (24u << 20)); // (B,H,64,T)
    unsigned short* xbuf   = (unsigned short*)(ws + (32u << 20)); // (M,K) bf16
    unsigned short* Wqkv_t = (unsigned short*)(ws + (40u << 20)); // (3D,D) bf16
    unsigned short* Wout_t = (unsigned short*)(ws + (46u << 20)); // (D,D) bf16
    float2*         ropeT  = (float2*)       (ws + (48u << 20)); // 2048x32 float2, 512 KB

    // 0) fused prep: convert x, transpose weights (vectorized), RoPE table
    prep_fused<<<dim3(3328), 256, 0, stream>>>(x, Wqkv, Wout, xbuf, Wqkv_t, Wout_t, ropeT);

    // 1) QKV MFMA GEMM (dbuf, XCD-affine) + RoPE table + scale + pack
    gemm_qkv_rope_mfma<<<dim3(768), 256, 0, stream>>>(xbuf, Wqkv_t, ropeT, Qb, Kb, Vt);

    // 2) MFMA causal flash attention v12 (paired softmax, shuffle-free path)
    attn_mfma12<<<dim3(1024), 256, 0, stream>>>(Qb, Kb, Vt, attnb);

    // 3) out = attnb @ Wout  (fp32 out, 128x64 tile, 2 blocks/CU)
    gemm_out_mfma<<<dim3(512), 256, 0, stream>>>(attnb, Wout_t, out, DMODEL, DMODEL);
}